// Round 7
// baseline (2196.030 us; speedup 1.0000x reference)
//
#include <hip/hip_runtime.h>

// Problem constants (fixed by reference)
constexpr int N_ = 2, T_ = 12, C_ = 64, H_ = 112, W_ = 112;
constexpr int HW_ = H_ * W_;
constexpr float SLOPE_ = 0.1f;
// Padded packed activation layout: rows -1..112 (114), cols -1..129 (131)
constexpr int PROW_ = 131;
constexpr int PNROW_ = 114;
constexpr int PPX_ = PROW_ * PNROW_;

typedef short bf16x8 __attribute__((ext_vector_type(8)));
typedef float f32x16 __attribute__((ext_vector_type(16)));

__device__ __forceinline__ unsigned short f2bf(float f) {
  unsigned u = __float_as_uint(f);
  unsigned r = (u + 0x7fffu + ((u >> 16) & 1u)) >> 16;
  return (unsigned short)r;
}
__device__ __forceinline__ float bf2f(unsigned short h) {
  return __uint_as_float(((unsigned)h) << 16);
}

// ---------------------------------------------------------------------------
// Bilinear sample with zero padding outside (matches reference flow_warp).
// ---------------------------------------------------------------------------
__device__ __forceinline__ float samp_one(const float* __restrict__ img, int y, int x) {
  if ((unsigned)x < (unsigned)W_ && (unsigned)y < (unsigned)H_)
    return img[y * W_ + x];
  return 0.f;
}

__device__ __forceinline__ float bilin(const float* __restrict__ img, float vx, float vy) {
  float x0f = floorf(vx), y0f = floorf(vy);
  int x0 = (int)x0f, y0 = (int)y0f;
  float wx = vx - x0f, wy = vy - y0f;
  float g00 = samp_one(img, y0,     x0);
  float g01 = samp_one(img, y0,     x0 + 1);
  float g10 = samp_one(img, y0 + 1, x0);
  float g11 = samp_one(img, y0 + 1, x0 + 1);
  return g00 * (1.f - wx) * (1.f - wy)
       + g01 * wx * (1.f - wy)
       + g10 * (1.f - wx) * wy
       + g11 * wx * wy;
}

// ---------------------------------------------------------------------------
// f2_tot = f1 + flow_warp(f2, f1)
// ---------------------------------------------------------------------------
__global__ __launch_bounds__(256) void f2tot_kernel(
    const float* __restrict__ f1, const float* __restrict__ f2,
    float* __restrict__ f2t) {
  int id = blockIdx.x * 256 + threadIdx.x;
  if (id >= N_ * HW_) return;
  int hw = id % HW_;
  int n  = id / HW_;
  int x = hw % W_, y = hw / W_;
  const float* f1n = f1 + (long)n * T_ * 2 * HW_;
  const float* f2n = f2 + (long)n * T_ * 2 * HW_;
  float vx = (float)x + f1n[hw];
  float vy = (float)y + f1n[HW_ + hw];
  float wfx = bilin(f2n,        vx, vy);
  float wfy = bilin(f2n + HW_,  vx, vy);
  f2t[((long)n * 2) * HW_ + hw]     = f1n[hw]       + wfx;
  f2t[((long)n * 2 + 1) * HW_ + hw] = f1n[HW_ + hw] + wfy;
}

// ---------------------------------------------------------------------------
// warp_pack: fused build_aggr + pack. Block = (n, icb 0..11, row y).
// slot = icb/4: 0=curr copy, 1=warp(p1,f1), 2=warp(p2,f2t); falls back to
// curr when p1/p2 null. Output padded packed hi/lo bf16 [n][12][PPX][16ic].
// ---------------------------------------------------------------------------
__global__ __launch_bounds__(256) void warp_pack(
    const float* __restrict__ curr,
    const float* __restrict__ p1,
    const float* __restrict__ p2,
    const float* __restrict__ f1,
    const float* __restrict__ f2t,
    short* __restrict__ xhi, short* __restrict__ xlo) {
  __shared__ float sm[16][113];
  __shared__ float sv[2][112];
  int bid = blockIdx.x;
  int y   = bid % H_;
  int icb = (bid / H_) % 12;
  int n   = bid / (H_ * 12);
  int tid = threadIdx.x;
  int slot = icb >> 2;
  int c0   = (icb & 3) * 16;
  long fn = (long)n * T_ * C_ * HW_;

  const float* src = nullptr;
  if (slot == 1 && p1) src = p1;
  if (slot == 2 && p2) src = p2;

  if (src == nullptr) {
    const float* cp = curr + fn + (long)c0 * HW_ + (long)y * W_;
    for (int i = tid; i < 16 * 112; i += 256) {
      int c = i / 112, x = i - c * 112;
      sm[c][x] = cp[(long)c * HW_ + x];
    }
  } else {
    if (tid < 112) {
      long hw = (long)y * W_ + tid;
      if (slot == 1) {
        const float* fp = f1 + (long)n * T_ * 2 * HW_;
        sv[0][tid] = (float)tid + fp[hw];
        sv[1][tid] = (float)y   + fp[HW_ + hw];
      } else {
        const float* fp = f2t + (long)n * 2 * HW_;
        sv[0][tid] = (float)tid + fp[hw];
        sv[1][tid] = (float)y   + fp[HW_ + hw];
      }
    }
    __syncthreads();
    const float* sp = src + fn + (long)c0 * HW_;
    for (int i = tid; i < 16 * 112; i += 256) {
      int c = i / 112, x = i - c * 112;
      sm[c][x] = bilin(sp + (long)c * HW_, sv[0][x], sv[1][x]);
    }
  }
  __syncthreads();
  if (tid < 224) {
    int px = tid >> 1, gg = tid & 1;
    unsigned hh[8], ll[8];
#pragma unroll
    for (int j = 0; j < 8; ++j) {
      float v = sm[gg * 8 + j][px];
      hh[j] = f2bf(v);
      ll[j] = f2bf(v - bf2f((unsigned short)hh[j]));
    }
    long o = ((long)(n * 12 + icb) * PPX_ + (long)(y + 1) * PROW_ + (px + 1)) * 16 + gg * 8;
    uint4 uh, ul;
    uh.x = hh[0] | (hh[1] << 16); uh.y = hh[2] | (hh[3] << 16);
    uh.z = hh[4] | (hh[5] << 16); uh.w = hh[6] | (hh[7] << 16);
    ul.x = ll[0] | (ll[1] << 16); ul.y = ll[2] | (ll[3] << 16);
    ul.z = ll[4] | (ll[5] << 16); ul.w = ll[6] | (ll[7] << 16);
    *(uint4*)(xhi + o) = uh;
    *(uint4*)(xlo + o) = ul;
  }
}

// ---------------------------------------------------------------------------
// pack_w: W (64, IC, 3, 3) fp32 -> MFMA A-fragment order, split hi/lo bf16.
// id -> [mt][tap][icb][lane][r]: oc = mt*32+(lane&31), ic = icb*16+(lane>>5)*8+r.
// ---------------------------------------------------------------------------
__global__ __launch_bounds__(256) void pack_w(
    const float* __restrict__ W, short* __restrict__ whi, short* __restrict__ wlo,
    int ICBC) {
  int id = blockIdx.x * 256 + threadIdx.x;
  int total = 2 * 9 * ICBC * 64 * 8;
  if (id >= total) return;
  int r    = id & 7;
  int lane = (id >> 3) & 63;
  int rest = id >> 9;
  int icb  = rest % ICBC;
  int mtt  = rest / ICBC;
  int tap  = mtt % 9;
  int mt   = mtt / 9;
  int oc = mt * 32 + (lane & 31);
  int ic = icb * 16 + ((lane >> 5) << 3) + r;
  int ky = tap / 3, kx = tap % 3;
  int IC = ICBC * 16;
  float v = W[(((long)oc * IC + ic) * 3 + ky) * 3 + kx];
  unsigned short h = f2bf(v);
  unsigned short l = f2bf(v - bf2f(h));
  whi[id] = (short)h;
  wlo[id] = (short)l;
}

// ---------------------------------------------------------------------------
// conv_mfma_p: 3x3 SAME conv partial, implicit-GEMM split-bf16 MFMA 32x32x16.
// NO LDS: x fragments read directly from the padded packed layout (block
// x-window is ~8.7KB -> L1-resident; taps re-read via L1). Weights read from
// fragment-ordered global (L2-resident). No barriers -> waves drift freely.
// Block = 256 thr (4 waves): wave = (mt = wid&1, row = wid>>1).
// blockIdx.z = n*KG + kg; each kg reduces NICB icb-blocks -> fp32 partial.
// 3 independent acc chains (WhXh / WlXh / WhXl).
// __launch_bounds__(256,2): 128-VGPR budget so the unrolled 9-tap loop's
// 36 loads software-pipeline (r5's (256,4)->60 VGPR serialized every tap).
// ---------------------------------------------------------------------------
template <int ICBT, int KG>
__global__ __launch_bounds__(256, 2) void conv_mfma_p(
    const short* __restrict__ xhi, const short* __restrict__ xlo,
    const short* __restrict__ whi, const short* __restrict__ wlo,
    float* __restrict__ part) {
  constexpr int NICB = ICBT / KG;
  const int tid  = threadIdx.x;
  const int lane = tid & 63;
  const int wid  = tid >> 6;
  const int mt   = wid & 1;
  const int row  = wid >> 1;
  const int g    = (lane >> 5) & 1;
  const int bx   = blockIdx.x * 32;
  const int by2  = blockIdx.y * 2;
  const int z    = blockIdx.z;
  const int kg   = z % KG;
  const int n    = z / KG;
  const int icb0 = kg * NICB;
  const int y    = by2 + row;
  const int xcol = bx + (lane & 31);

  f32x16 accA, accB, accC;
#pragma unroll
  for (int i = 0; i < 16; ++i) { accA[i] = 0.f; accB[i] = 0.f; accC[i] = 0.f; }

  // x: ((n*ICBT+icb)*PPX + (y+dy)*PROW + xcol+dx)*16 + g*8   (shorts)
  // w: (((mt*9+tap)*ICBT + icb)*64 + lane)*8                 (shorts)
  long xoff = ((long)(n * ICBT + icb0) * PPX_ + (long)y * PROW_ + xcol) * 16 + g * 8;
  long woff = ((long)(mt * 9 * ICBT + icb0)) * 512 + lane * 8;

  for (int ii = 0; ii < NICB; ++ii) {
    const short* xh_b = xhi + xoff;
    const short* xl_b = xlo + xoff;
    const short* wh_b = whi + woff;
    const short* wl_b = wlo + woff;
#pragma unroll
    for (int tap = 0; tap < 9; ++tap) {
      const int dy = tap / 3, dx = tap % 3;
      const long xo = ((long)dy * PROW_ + dx) * 16;
      const long wo = (long)tap * ICBT * 512;
      bf16x8 xh = *(const bf16x8*)(xh_b + xo);
      bf16x8 xl = *(const bf16x8*)(xl_b + xo);
      bf16x8 wh = *(const bf16x8*)(wh_b + wo);
      bf16x8 wl = *(const bf16x8*)(wl_b + wo);
      accA = __builtin_amdgcn_mfma_f32_32x32x16_bf16(wh, xh, accA, 0, 0, 0);
      accB = __builtin_amdgcn_mfma_f32_32x32x16_bf16(wl, xh, accB, 0, 0, 0);
      accC = __builtin_amdgcn_mfma_f32_32x32x16_bf16(wh, xl, accC, 0, 0, 0);
    }
    xoff += (long)PPX_ * 16;
    woff += 512;
  }

  int pxg = bx + (lane & 31);
  if (pxg < W_) {
    long base = (long)z * 64 * HW_ + (long)y * W_ + pxg;
#pragma unroll
    for (int r = 0; r < 16; ++r) {
      int oc = mt * 32 + (r & 3) + 8 * (r >> 2) + 4 * g;
      part[base + (long)oc * HW_] = accA[r] + accB[r] + accC[r];
    }
  }
}

// ---------------------------------------------------------------------------
// combine1: h1 = lrelu(sum_kg part + bias) -> packed padded hi/lo (conv2 in).
// KG1=4 partials. Block = (n, icb 0..3, row y).
// ---------------------------------------------------------------------------
__global__ __launch_bounds__(256) void combine1(
    const float* __restrict__ part, const float* __restrict__ bias,
    short* __restrict__ ohi, short* __restrict__ olo) {
  __shared__ float sm[16][113];
  int bid = blockIdx.x;
  int y   = bid % H_;
  int icb = (bid / H_) % 4;
  int n   = bid / (H_ * 4);
  int tid = threadIdx.x;
  for (int i = tid; i < 16 * 112; i += 256) {
    int c = i / 112, x = i - c * 112;
    int oc = icb * 16 + c;
    long hw = (long)y * W_ + x;
    float v = part[((long)(n * 4 + 0) * 64 + oc) * HW_ + hw]
            + part[((long)(n * 4 + 1) * 64 + oc) * HW_ + hw]
            + part[((long)(n * 4 + 2) * 64 + oc) * HW_ + hw]
            + part[((long)(n * 4 + 3) * 64 + oc) * HW_ + hw]
            + bias[oc];
    v = v > 0.f ? v : v * SLOPE_;
    sm[c][x] = v;
  }
  __syncthreads();
  if (tid < 224) {
    int px = tid >> 1, gg = tid & 1;
    unsigned hh[8], ll[8];
#pragma unroll
    for (int j = 0; j < 8; ++j) {
      float v = sm[gg * 8 + j][px];
      hh[j] = f2bf(v);
      ll[j] = f2bf(v - bf2f((unsigned short)hh[j]));
    }
    long o = ((long)(n * 4 + icb) * PPX_ + (long)(y + 1) * PROW_ + (px + 1)) * 16 + gg * 8;
    uint4 uh, ul;
    uh.x = hh[0] | (hh[1] << 16); uh.y = hh[2] | (hh[3] << 16);
    uh.z = hh[4] | (hh[5] << 16); uh.w = hh[6] | (hh[7] << 16);
    ul.x = ll[0] | (ll[1] << 16); ul.y = ll[2] | (ll[3] << 16);
    ul.z = ll[4] | (ll[5] << 16); ul.w = ll[6] | (ll[7] << 16);
    *(uint4*)(ohi + o) = uh;
    *(uint4*)(olo + o) = ul;
  }
}

// ---------------------------------------------------------------------------
// combine2: out[t] += sum_kg part + bias (residual already in out[t]). KG2=2.
// ---------------------------------------------------------------------------
__global__ __launch_bounds__(256) void combine2(
    const float* __restrict__ part, const float* __restrict__ bias,
    float* __restrict__ out_t) {
  int id = blockIdx.x * 256 + threadIdx.x;
  if (id >= N_ * C_ * HW_) return;
  int hw = id % HW_;
  int oc = (id / HW_) % C_;
  int n  = id / (HW_ * C_);
  long o = (long)n * T_ * C_ * HW_ + (long)oc * HW_ + hw;
  float v = part[((long)(n * 2 + 0) * 64 + oc) * HW_ + hw]
          + part[((long)(n * 2 + 1) * 64 + oc) * HW_ + hw]
          + bias[oc] + out_t[o];
  out_t[o] = v;
}

// ---------------------------------------------------------------------------
// Host-side orchestration
// ---------------------------------------------------------------------------
struct Bufs {
  float* f2t; float* part;
  short *xhi, *xlo, *h1hi, *h1lo, *w1hi, *w1lo, *w2hi, *w2lo;
};

static void run_step(float* out, const float* flows, int t, bool fwd, int i,
                     const float* b1, const float* b2, const Bufs& B,
                     hipStream_t stream) {
  const float* curr = out + (long)t * C_ * HW_;
  const float* p1 = nullptr;
  const float* p2 = nullptr;
  const float* f1 = nullptr;
  const float* f2 = nullptr;
  if (fwd) {
    if (t >= 1) { p1 = out + (long)(t - 1) * C_ * HW_; f1 = flows + (long)(t - 1) * 2 * HW_; }
    if (t >= 2) { p2 = out + (long)(t - 2) * C_ * HW_; f2 = flows + (long)(t - 2) * 2 * HW_; }
  } else {
    if (i >= 1) { p1 = out + (long)(t + 1) * C_ * HW_; f1 = flows + (long)(t + 1) * 2 * HW_; }
    if (i >= 2) { p2 = out + (long)(t + 2) * C_ * HW_; f2 = flows + (long)(t + 2) * 2 * HW_; }
  }

  if (p2) {
    int nb = (N_ * HW_ + 255) / 256;
    f2tot_kernel<<<nb, 256, 0, stream>>>(f1, f2, B.f2t);
  }
  warp_pack<<<N_ * 12 * H_, 256, 0, stream>>>(curr, p1, p2, f1, B.f2t, B.xhi, B.xlo);
  // conv1: KG=4 -> 1792 blocks
  conv_mfma_p<12, 4><<<dim3(4, 56, N_ * 4), 256, 0, stream>>>(
      B.xhi, B.xlo, B.w1hi, B.w1lo, B.part);
  combine1<<<N_ * 4 * H_, 256, 0, stream>>>(B.part, b1, B.h1hi, B.h1lo);
  // conv2: KG=2 -> 896 blocks (part traffic balance)
  conv_mfma_p<4, 2><<<dim3(4, 56, N_ * 2), 256, 0, stream>>>(
      B.h1hi, B.h1lo, B.w2hi, B.w2lo, B.part);
  combine2<<<(N_ * C_ * HW_ + 255) / 256, 256, 0, stream>>>(
      B.part, b2, out + (long)t * C_ * HW_);
}

extern "C" void kernel_launch(void* const* d_in, const int* in_sizes, int n_in,
                              void* d_out, int out_size, void* d_ws, size_t ws_size,
                              hipStream_t stream) {
  const float* feats = (const float*)d_in[0];
  const float* fflow = (const float*)d_in[1];
  const float* bflow = (const float*)d_in[2];
  const float* W1 = (const float*)d_in[3];
  const float* b1 = (const float*)d_in[4];
  const float* W2 = (const float*)d_in[5];
  const float* b2 = (const float*)d_in[6];
  float* out = (float*)d_out;

  char* p = (char*)d_ws;
  auto carve = [&](size_t bytes) {
    void* r = (void*)p;
    p += (bytes + 255) & ~(size_t)255;
    return r;
  };
  Bufs B;
  size_t xpack_sh  = (size_t)N_ * 12 * PPX_ * 16;
  size_t h1pack_sh = (size_t)N_ * 4 * PPX_ * 16;
  B.f2t  = (float*)carve(sizeof(float) * N_ * 2 * HW_);
  B.part = (float*)carve(sizeof(float) * (size_t)4 * N_ * 64 * HW_);  // KG up to 4
  B.xhi  = (short*)carve(2 * xpack_sh);
  B.xlo  = (short*)carve(2 * xpack_sh);
  B.h1hi = (short*)carve(2 * h1pack_sh);
  B.h1lo = (short*)carve(2 * h1pack_sh);
  B.w1hi = (short*)carve(2 * (size_t)(2 * 9 * 12 * 64 * 8));
  B.w1lo = (short*)carve(2 * (size_t)(2 * 9 * 12 * 64 * 8));
  B.w2hi = (short*)carve(2 * (size_t)(2 * 9 * 4 * 64 * 8));
  B.w2lo = (short*)carve(2 * (size_t)(2 * 9 * 4 * 64 * 8));

  // Zero packed buffers once per launch (zeros the conv padding halos).
  hipMemsetAsync(B.xhi, 0, 2 * xpack_sh, stream);
  hipMemsetAsync(B.xlo, 0, 2 * xpack_sh, stream);
  hipMemsetAsync(B.h1hi, 0, 2 * h1pack_sh, stream);
  hipMemsetAsync(B.h1lo, 0, 2 * h1pack_sh, stream);

  // Weight fragments (hi/lo split), once per launch.
  pack_w<<<(2 * 9 * 12 * 64 * 8 + 255) / 256, 256, 0, stream>>>(W1, B.w1hi, B.w1lo, 12);
  pack_w<<<(2 * 9 * 4 * 64 * 8 + 255) / 256, 256, 0, stream>>>(W2, B.w2hi, B.w2lo, 4);

  // Seed the working feats (in d_out) with the input feats.
  hipMemcpyAsync(out, feats, sizeof(float) * (size_t)N_ * T_ * C_ * HW_,
                 hipMemcpyDeviceToDevice, stream);

  for (int t = 0; t < T_; ++t)
    run_step(out, fflow, t, true, t, b1, b2, B, stream);
  for (int i = 0; i < T_; ++i) {
    int t = T_ - 1 - i;
    run_step(out, bflow, t, false, i, b1, b2, B, stream);
  }
}

// Round 8
// 2072.975 us; speedup vs baseline: 1.0594x; 1.0594x over previous
//
#include <hip/hip_runtime.h>

// Problem constants (fixed by reference)
constexpr int N_ = 2, T_ = 12, C_ = 64, H_ = 112, W_ = 112;
constexpr int HW_ = H_ * W_;
constexpr float SLOPE_ = 0.1f;
// Padded packed activation layout: rows -1..112 (114), cols -1..129 (131)
constexpr int PROW_ = 131;
constexpr int PNROW_ = 114;
constexpr int PPX_ = PROW_ * PNROW_;

typedef short bf16x8 __attribute__((ext_vector_type(8)));
typedef float f32x16 __attribute__((ext_vector_type(16)));

__device__ __forceinline__ unsigned short f2bf(float f) {
  unsigned u = __float_as_uint(f);
  unsigned r = (u + 0x7fffu + ((u >> 16) & 1u)) >> 16;
  return (unsigned short)r;
}
__device__ __forceinline__ float bf2f(unsigned short h) {
  return __uint_as_float(((unsigned)h) << 16);
}

// ---------------------------------------------------------------------------
// Bilinear sample with zero padding outside (matches reference flow_warp).
// ---------------------------------------------------------------------------
__device__ __forceinline__ float samp_one(const float* __restrict__ img, int y, int x) {
  if ((unsigned)x < (unsigned)W_ && (unsigned)y < (unsigned)H_)
    return img[y * W_ + x];
  return 0.f;
}

__device__ __forceinline__ float bilin(const float* __restrict__ img, float vx, float vy) {
  float x0f = floorf(vx), y0f = floorf(vy);
  int x0 = (int)x0f, y0 = (int)y0f;
  float wx = vx - x0f, wy = vy - y0f;
  float g00 = samp_one(img, y0,     x0);
  float g01 = samp_one(img, y0,     x0 + 1);
  float g10 = samp_one(img, y0 + 1, x0);
  float g11 = samp_one(img, y0 + 1, x0 + 1);
  return g00 * (1.f - wx) * (1.f - wy)
       + g01 * wx * (1.f - wy)
       + g10 * (1.f - wx) * wy
       + g11 * wx * wy;
}

// ---------------------------------------------------------------------------
// f2_tot = f1 + flow_warp(f2, f1)
// ---------------------------------------------------------------------------
__global__ __launch_bounds__(256) void f2tot_kernel(
    const float* __restrict__ f1, const float* __restrict__ f2,
    float* __restrict__ f2t) {
  int id = blockIdx.x * 256 + threadIdx.x;
  if (id >= N_ * HW_) return;
  int hw = id % HW_;
  int n  = id / HW_;
  int x = hw % W_, y = hw / W_;
  const float* f1n = f1 + (long)n * T_ * 2 * HW_;
  const float* f2n = f2 + (long)n * T_ * 2 * HW_;
  float vx = (float)x + f1n[hw];
  float vy = (float)y + f1n[HW_ + hw];
  float wfx = bilin(f2n,        vx, vy);
  float wfy = bilin(f2n + HW_,  vx, vy);
  f2t[((long)n * 2) * HW_ + hw]     = f1n[hw]       + wfx;
  f2t[((long)n * 2 + 1) * HW_ + hw] = f1n[HW_ + hw] + wfy;
}

// ---------------------------------------------------------------------------
// warp_pack: fused build_aggr + pack. Block = (n, icb 0..11, row y).
// slot = icb/4: 0=curr copy, 1=warp(p1,f1), 2=warp(p2,f2t); falls back to
// curr when p1/p2 null. Output padded packed hi/lo bf16 [n][12][PPX][16ic].
// ---------------------------------------------------------------------------
__global__ __launch_bounds__(256) void warp_pack(
    const float* __restrict__ curr,
    const float* __restrict__ p1,
    const float* __restrict__ p2,
    const float* __restrict__ f1,
    const float* __restrict__ f2t,
    short* __restrict__ xhi, short* __restrict__ xlo) {
  __shared__ float sm[16][113];
  __shared__ float sv[2][112];
  int bid = blockIdx.x;
  int y   = bid % H_;
  int icb = (bid / H_) % 12;
  int n   = bid / (H_ * 12);
  int tid = threadIdx.x;
  int slot = icb >> 2;
  int c0   = (icb & 3) * 16;
  long fn = (long)n * T_ * C_ * HW_;

  const float* src = nullptr;
  if (slot == 1 && p1) src = p1;
  if (slot == 2 && p2) src = p2;

  if (src == nullptr) {
    const float* cp = curr + fn + (long)c0 * HW_ + (long)y * W_;
    for (int i = tid; i < 16 * 112; i += 256) {
      int c = i / 112, x = i - c * 112;
      sm[c][x] = cp[(long)c * HW_ + x];
    }
  } else {
    if (tid < 112) {
      long hw = (long)y * W_ + tid;
      if (slot == 1) {
        const float* fp = f1 + (long)n * T_ * 2 * HW_;
        sv[0][tid] = (float)tid + fp[hw];
        sv[1][tid] = (float)y   + fp[HW_ + hw];
      } else {
        const float* fp = f2t + (long)n * 2 * HW_;
        sv[0][tid] = (float)tid + fp[hw];
        sv[1][tid] = (float)y   + fp[HW_ + hw];
      }
    }
    __syncthreads();
    const float* sp = src + fn + (long)c0 * HW_;
    for (int i = tid; i < 16 * 112; i += 256) {
      int c = i / 112, x = i - c * 112;
      sm[c][x] = bilin(sp + (long)c * HW_, sv[0][x], sv[1][x]);
    }
  }
  __syncthreads();
  if (tid < 224) {
    int px = tid >> 1, gg = tid & 1;
    unsigned hh[8], ll[8];
#pragma unroll
    for (int j = 0; j < 8; ++j) {
      float v = sm[gg * 8 + j][px];
      hh[j] = f2bf(v);
      ll[j] = f2bf(v - bf2f((unsigned short)hh[j]));
    }
    long o = ((long)(n * 12 + icb) * PPX_ + (long)(y + 1) * PROW_ + (px + 1)) * 16 + gg * 8;
    uint4 uh, ul;
    uh.x = hh[0] | (hh[1] << 16); uh.y = hh[2] | (hh[3] << 16);
    uh.z = hh[4] | (hh[5] << 16); uh.w = hh[6] | (hh[7] << 16);
    ul.x = ll[0] | (ll[1] << 16); ul.y = ll[2] | (ll[3] << 16);
    ul.z = ll[4] | (ll[5] << 16); ul.w = ll[6] | (ll[7] << 16);
    *(uint4*)(xhi + o) = uh;
    *(uint4*)(xlo + o) = ul;
  }
}

// ---------------------------------------------------------------------------
// pack_w: W (64, IC, 3, 3) fp32 -> MFMA A-fragment order, split hi/lo bf16.
// id -> [mt][tap][icb][lane][r]: oc = mt*32+(lane&31), ic = icb*16+(lane>>5)*8+r.
// ---------------------------------------------------------------------------
__global__ __launch_bounds__(256) void pack_w(
    const float* __restrict__ W, short* __restrict__ whi, short* __restrict__ wlo,
    int ICBC) {
  int id = blockIdx.x * 256 + threadIdx.x;
  int total = 2 * 9 * ICBC * 64 * 8;
  if (id >= total) return;
  int r    = id & 7;
  int lane = (id >> 3) & 63;
  int rest = id >> 9;
  int icb  = rest % ICBC;
  int mtt  = rest / ICBC;
  int tap  = mtt % 9;
  int mt   = mtt / 9;
  int oc = mt * 32 + (lane & 31);
  int ic = icb * 16 + ((lane >> 5) << 3) + r;
  int ky = tap / 3, kx = tap % 3;
  int IC = ICBC * 16;
  float v = W[(((long)oc * IC + ic) * 3 + ky) * 3 + kx];
  unsigned short h = f2bf(v);
  unsigned short l = f2bf(v - bf2f(h));
  whi[id] = (short)h;
  wlo[id] = (short)l;
}

// ---------------------------------------------------------------------------
// conv_mfma_p: 3x3 SAME conv partial, implicit-GEMM split-bf16 MFMA 32x32x16.
// No LDS; x and weights read directly from global (L1/L2). The (icb, tap)
// loops are FLATTENED into NIT = NICB*9 fully-unrolled iterations and
// SOFTWARE-PIPELINED 2 deep in source with named fragment sets (f0, f1, fn):
// r7 showed hipcc will not pipeline on its own (kept VGPR=56, serial
// load->wait->mfma per tap, 46us, MfmaUtil 16%). The explicit rotation in a
// fully-unrolled loop is SSA renaming -> ~12 outstanding 16B loads/wave.
// Block = 256 thr (4 waves): wave = (mt = wid&1, row = wid>>1).
// blockIdx.z = n*KG + kg; each kg reduces NICB icb-blocks -> fp32 partial.
// 3 independent acc chains (WhXh / WlXh / WhXl).
// ---------------------------------------------------------------------------
struct Frags { bf16x8 xh, xl, wh, wl; };

template <int ICBT, int KG>
__global__ __launch_bounds__(256) void conv_mfma_p(
    const short* __restrict__ xhi, const short* __restrict__ xlo,
    const short* __restrict__ whi, const short* __restrict__ wlo,
    float* __restrict__ part) {
  constexpr int NICB = ICBT / KG;
  constexpr int NIT  = NICB * 9;
  const int tid  = threadIdx.x;
  const int lane = tid & 63;
  const int wid  = tid >> 6;
  const int mt   = wid & 1;
  const int row  = wid >> 1;
  const int g    = (lane >> 5) & 1;
  const int bx   = blockIdx.x * 32;
  const int by2  = blockIdx.y * 2;
  const int z    = blockIdx.z;
  const int kg   = z % KG;
  const int n    = z / KG;
  const int icb0 = kg * NICB;
  const int y    = by2 + row;
  const int xcol = bx + (lane & 31);

  f32x16 accA, accB, accC;
#pragma unroll
  for (int i = 0; i < 16; ++i) { accA[i] = 0.f; accB[i] = 0.f; accC[i] = 0.f; }

  // x: ((n*ICBT+icb0+ii)*PPX + (y+dy)*PROW + xcol+dx)*16 + g*8   (shorts)
  // w: ((mt*9*ICBT + icb0) + tap*ICBT + ii)*512 + lane*8         (shorts)
  const short* xh_p = xhi + ((long)(n * ICBT + icb0) * PPX_ + (long)y * PROW_ + xcol) * 16 + g * 8;
  const short* xl_p = xlo + ((long)(n * ICBT + icb0) * PPX_ + (long)y * PROW_ + xcol) * 16 + g * 8;
  const short* wh_p = whi + ((long)(mt * 9 * ICBT + icb0)) * 512 + lane * 8;
  const short* wl_p = wlo + ((long)(mt * 9 * ICBT + icb0)) * 512 + lane * 8;

  auto ld = [&](int it) {
    const int ii = it / 9, tap = it % 9;
    const int dy = tap / 3, dx = tap % 3;
    const long xo = ((long)ii * PPX_ + (long)dy * PROW_ + dx) * 16;
    const long wo = ((long)(tap * ICBT + ii)) * 512;
    Frags f;
    f.xh = *(const bf16x8*)(xh_p + xo);
    f.xl = *(const bf16x8*)(xl_p + xo);
    f.wh = *(const bf16x8*)(wh_p + wo);
    f.wl = *(const bf16x8*)(wl_p + wo);
    return f;
  };

  Frags f0 = ld(0);
  Frags f1 = (NIT > 1) ? ld(1) : f0;
#pragma unroll
  for (int it = 0; it < NIT; ++it) {
    Frags fn = f1;
    if (it + 2 < NIT) fn = ld(it + 2);
    accA = __builtin_amdgcn_mfma_f32_32x32x16_bf16(f0.wh, f0.xh, accA, 0, 0, 0);
    accB = __builtin_amdgcn_mfma_f32_32x32x16_bf16(f0.wl, f0.xh, accB, 0, 0, 0);
    accC = __builtin_amdgcn_mfma_f32_32x32x16_bf16(f0.wh, f0.xl, accC, 0, 0, 0);
    f0 = f1;
    f1 = fn;
  }

  int pxg = bx + (lane & 31);
  if (pxg < W_) {
    long base = (long)z * 64 * HW_ + (long)y * W_ + pxg;
#pragma unroll
    for (int r = 0; r < 16; ++r) {
      int oc = mt * 32 + (r & 3) + 8 * (r >> 2) + 4 * g;
      part[base + (long)oc * HW_] = accA[r] + accB[r] + accC[r];
    }
  }
}

// ---------------------------------------------------------------------------
// combine1: h1 = lrelu(sum_kg part + bias) -> packed padded hi/lo (conv2 in).
// KG1 partials. Block = (n, icb 0..3, row y).
// ---------------------------------------------------------------------------
template <int KG>
__global__ __launch_bounds__(256) void combine1(
    const float* __restrict__ part, const float* __restrict__ bias,
    short* __restrict__ ohi, short* __restrict__ olo) {
  __shared__ float sm[16][113];
  int bid = blockIdx.x;
  int y   = bid % H_;
  int icb = (bid / H_) % 4;
  int n   = bid / (H_ * 4);
  int tid = threadIdx.x;
  for (int i = tid; i < 16 * 112; i += 256) {
    int c = i / 112, x = i - c * 112;
    int oc = icb * 16 + c;
    long hw = (long)y * W_ + x;
    float v = bias[oc];
#pragma unroll
    for (int k = 0; k < KG; ++k)
      v += part[((long)(n * KG + k) * 64 + oc) * HW_ + hw];
    v = v > 0.f ? v : v * SLOPE_;
    sm[c][x] = v;
  }
  __syncthreads();
  if (tid < 224) {
    int px = tid >> 1, gg = tid & 1;
    unsigned hh[8], ll[8];
#pragma unroll
    for (int j = 0; j < 8; ++j) {
      float v = sm[gg * 8 + j][px];
      hh[j] = f2bf(v);
      ll[j] = f2bf(v - bf2f((unsigned short)hh[j]));
    }
    long o = ((long)(n * 4 + icb) * PPX_ + (long)(y + 1) * PROW_ + (px + 1)) * 16 + gg * 8;
    uint4 uh, ul;
    uh.x = hh[0] | (hh[1] << 16); uh.y = hh[2] | (hh[3] << 16);
    uh.z = hh[4] | (hh[5] << 16); uh.w = hh[6] | (hh[7] << 16);
    ul.x = ll[0] | (ll[1] << 16); ul.y = ll[2] | (ll[3] << 16);
    ul.z = ll[4] | (ll[5] << 16); ul.w = ll[6] | (ll[7] << 16);
    *(uint4*)(ohi + o) = uh;
    *(uint4*)(olo + o) = ul;
  }
}

// ---------------------------------------------------------------------------
// combine2: out[t] += sum_kg part + bias (residual already in out[t]).
// ---------------------------------------------------------------------------
template <int KG>
__global__ __launch_bounds__(256) void combine2(
    const float* __restrict__ part, const float* __restrict__ bias,
    float* __restrict__ out_t) {
  int id = blockIdx.x * 256 + threadIdx.x;
  if (id >= N_ * C_ * HW_) return;
  int hw = id % HW_;
  int oc = (id / HW_) % C_;
  int n  = id / (HW_ * C_);
  long o = (long)n * T_ * C_ * HW_ + (long)oc * HW_ + hw;
  float v = bias[oc] + out_t[o];
#pragma unroll
  for (int k = 0; k < KG; ++k)
    v += part[((long)(n * KG + k) * 64 + oc) * HW_ + hw];
  out_t[o] = v;
}

// ---------------------------------------------------------------------------
// Host-side orchestration
// ---------------------------------------------------------------------------
constexpr int KG1 = 6;   // conv1 K-split (NICB=2, 2688 blocks)
constexpr int KG2 = 4;   // conv2 K-split (NICB=1, 1792 blocks)

struct Bufs {
  float* f2t; float* part;
  short *xhi, *xlo, *h1hi, *h1lo, *w1hi, *w1lo, *w2hi, *w2lo;
};

static void run_step(float* out, const float* flows, int t, bool fwd, int i,
                     const float* b1, const float* b2, const Bufs& B,
                     hipStream_t stream) {
  const float* curr = out + (long)t * C_ * HW_;
  const float* p1 = nullptr;
  const float* p2 = nullptr;
  const float* f1 = nullptr;
  const float* f2 = nullptr;
  if (fwd) {
    if (t >= 1) { p1 = out + (long)(t - 1) * C_ * HW_; f1 = flows + (long)(t - 1) * 2 * HW_; }
    if (t >= 2) { p2 = out + (long)(t - 2) * C_ * HW_; f2 = flows + (long)(t - 2) * 2 * HW_; }
  } else {
    if (i >= 1) { p1 = out + (long)(t + 1) * C_ * HW_; f1 = flows + (long)(t + 1) * 2 * HW_; }
    if (i >= 2) { p2 = out + (long)(t + 2) * C_ * HW_; f2 = flows + (long)(t + 2) * 2 * HW_; }
  }

  if (p2) {
    int nb = (N_ * HW_ + 255) / 256;
    f2tot_kernel<<<nb, 256, 0, stream>>>(f1, f2, B.f2t);
  }
  warp_pack<<<N_ * 12 * H_, 256, 0, stream>>>(curr, p1, p2, f1, B.f2t, B.xhi, B.xlo);
  conv_mfma_p<12, KG1><<<dim3(4, 56, N_ * KG1), 256, 0, stream>>>(
      B.xhi, B.xlo, B.w1hi, B.w1lo, B.part);
  combine1<KG1><<<N_ * 4 * H_, 256, 0, stream>>>(B.part, b1, B.h1hi, B.h1lo);
  conv_mfma_p<4, KG2><<<dim3(4, 56, N_ * KG2), 256, 0, stream>>>(
      B.h1hi, B.h1lo, B.w2hi, B.w2lo, B.part);
  combine2<KG2><<<(N_ * C_ * HW_ + 255) / 256, 256, 0, stream>>>(
      B.part, b2, out + (long)t * C_ * HW_);
}

extern "C" void kernel_launch(void* const* d_in, const int* in_sizes, int n_in,
                              void* d_out, int out_size, void* d_ws, size_t ws_size,
                              hipStream_t stream) {
  const float* feats = (const float*)d_in[0];
  const float* fflow = (const float*)d_in[1];
  const float* bflow = (const float*)d_in[2];
  const float* W1 = (const float*)d_in[3];
  const float* b1 = (const float*)d_in[4];
  const float* W2 = (const float*)d_in[5];
  const float* b2 = (const float*)d_in[6];
  float* out = (float*)d_out;

  char* p = (char*)d_ws;
  auto carve = [&](size_t bytes) {
    void* r = (void*)p;
    p += (bytes + 255) & ~(size_t)255;
    return r;
  };
  Bufs B;
  size_t xpack_sh  = (size_t)N_ * 12 * PPX_ * 16;
  size_t h1pack_sh = (size_t)N_ * 4 * PPX_ * 16;
  B.f2t  = (float*)carve(sizeof(float) * N_ * 2 * HW_);
  B.part = (float*)carve(sizeof(float) * (size_t)KG1 * N_ * 64 * HW_);
  B.xhi  = (short*)carve(2 * xpack_sh);
  B.xlo  = (short*)carve(2 * xpack_sh);
  B.h1hi = (short*)carve(2 * h1pack_sh);
  B.h1lo = (short*)carve(2 * h1pack_sh);
  B.w1hi = (short*)carve(2 * (size_t)(2 * 9 * 12 * 64 * 8));
  B.w1lo = (short*)carve(2 * (size_t)(2 * 9 * 12 * 64 * 8));
  B.w2hi = (short*)carve(2 * (size_t)(2 * 9 * 4 * 64 * 8));
  B.w2lo = (short*)carve(2 * (size_t)(2 * 9 * 4 * 64 * 8));

  // Zero packed buffers once per launch (zeros the conv padding halos).
  hipMemsetAsync(B.xhi, 0, 2 * xpack_sh, stream);
  hipMemsetAsync(B.xlo, 0, 2 * xpack_sh, stream);
  hipMemsetAsync(B.h1hi, 0, 2 * h1pack_sh, stream);
  hipMemsetAsync(B.h1lo, 0, 2 * h1pack_sh, stream);

  // Weight fragments (hi/lo split), once per launch.
  pack_w<<<(2 * 9 * 12 * 64 * 8 + 255) / 256, 256, 0, stream>>>(W1, B.w1hi, B.w1lo, 12);
  pack_w<<<(2 * 9 * 4 * 64 * 8 + 255) / 256, 256, 0, stream>>>(W2, B.w2hi, B.w2lo, 4);

  // Seed the working feats (in d_out) with the input feats.
  hipMemcpyAsync(out, feats, sizeof(float) * (size_t)N_ * T_ * C_ * HW_,
                 hipMemcpyDeviceToDevice, stream);

  for (int t = 0; t < T_; ++t)
    run_step(out, fflow, t, true, t, b1, b2, B, stream);
  for (int i = 0; i < T_; ++i) {
    int t = T_ - 1 - i;
    run_step(out, bflow, t, false, i, b1, b2, B, stream);
  }
}

// Round 9
// 2040.124 us; speedup vs baseline: 1.0764x; 1.0161x over previous
//
#include <hip/hip_runtime.h>

// Problem constants (fixed by reference)
constexpr int N_ = 2, T_ = 12, C_ = 64, H_ = 112, W_ = 112;
constexpr int HW_ = H_ * W_;
constexpr float SLOPE_ = 0.1f;
// Padded packed activation layout: rows -1..112 (114), cols -1..129 (131)
constexpr int PROW_ = 131;
constexpr int PNROW_ = 114;
constexpr int PPX_ = PROW_ * PNROW_;

typedef short bf16x8 __attribute__((ext_vector_type(8)));
typedef float f32x16 __attribute__((ext_vector_type(16)));

__device__ __forceinline__ unsigned short f2bf(float f) {
  unsigned u = __float_as_uint(f);
  unsigned r = (u + 0x7fffu + ((u >> 16) & 1u)) >> 16;
  return (unsigned short)r;
}
__device__ __forceinline__ float bf2f(unsigned short h) {
  return __uint_as_float(((unsigned)h) << 16);
}

// ---------------------------------------------------------------------------
// Bilinear sample with zero padding outside (matches reference flow_warp).
// ---------------------------------------------------------------------------
__device__ __forceinline__ float samp_one(const float* __restrict__ img, int y, int x) {
  if ((unsigned)x < (unsigned)W_ && (unsigned)y < (unsigned)H_)
    return img[y * W_ + x];
  return 0.f;
}

__device__ __forceinline__ float bilin(const float* __restrict__ img, float vx, float vy) {
  float x0f = floorf(vx), y0f = floorf(vy);
  int x0 = (int)x0f, y0 = (int)y0f;
  float wx = vx - x0f, wy = vy - y0f;
  float g00 = samp_one(img, y0,     x0);
  float g01 = samp_one(img, y0,     x0 + 1);
  float g10 = samp_one(img, y0 + 1, x0);
  float g11 = samp_one(img, y0 + 1, x0 + 1);
  return g00 * (1.f - wx) * (1.f - wy)
       + g01 * wx * (1.f - wy)
       + g10 * (1.f - wx) * wy
       + g11 * wx * wy;
}

// ---------------------------------------------------------------------------
// f2_tot = f1 + flow_warp(f2, f1)
// ---------------------------------------------------------------------------
__global__ __launch_bounds__(256) void f2tot_kernel(
    const float* __restrict__ f1, const float* __restrict__ f2,
    float* __restrict__ f2t) {
  int id = blockIdx.x * 256 + threadIdx.x;
  if (id >= N_ * HW_) return;
  int hw = id % HW_;
  int n  = id / HW_;
  int x = hw % W_, y = hw / W_;
  const float* f1n = f1 + (long)n * T_ * 2 * HW_;
  const float* f2n = f2 + (long)n * T_ * 2 * HW_;
  float vx = (float)x + f1n[hw];
  float vy = (float)y + f1n[HW_ + hw];
  float wfx = bilin(f2n,        vx, vy);
  float wfy = bilin(f2n + HW_,  vx, vy);
  f2t[((long)n * 2) * HW_ + hw]     = f1n[hw]       + wfx;
  f2t[((long)n * 2 + 1) * HW_ + hw] = f1n[HW_ + hw] + wfy;
}

// ---------------------------------------------------------------------------
// warp_pack: fused build_aggr + pack. Block = (n, icb 0..11, row y).
// slot = icb/4: 0=curr copy, 1=warp(p1,f1), 2=warp(p2,f2t); falls back to
// curr when p1/p2 null. Output padded packed hi/lo bf16 [n][12][PPX][16ic].
// ---------------------------------------------------------------------------
__global__ __launch_bounds__(256) void warp_pack(
    const float* __restrict__ curr,
    const float* __restrict__ p1,
    const float* __restrict__ p2,
    const float* __restrict__ f1,
    const float* __restrict__ f2t,
    short* __restrict__ xhi, short* __restrict__ xlo) {
  __shared__ float sm[16][113];
  __shared__ float sv[2][112];
  int bid = blockIdx.x;
  int y   = bid % H_;
  int icb = (bid / H_) % 12;
  int n   = bid / (H_ * 12);
  int tid = threadIdx.x;
  int slot = icb >> 2;
  int c0   = (icb & 3) * 16;
  long fn = (long)n * T_ * C_ * HW_;

  const float* src = nullptr;
  if (slot == 1 && p1) src = p1;
  if (slot == 2 && p2) src = p2;

  if (src == nullptr) {
    const float* cp = curr + fn + (long)c0 * HW_ + (long)y * W_;
    for (int i = tid; i < 16 * 112; i += 256) {
      int c = i / 112, x = i - c * 112;
      sm[c][x] = cp[(long)c * HW_ + x];
    }
  } else {
    if (tid < 112) {
      long hw = (long)y * W_ + tid;
      if (slot == 1) {
        const float* fp = f1 + (long)n * T_ * 2 * HW_;
        sv[0][tid] = (float)tid + fp[hw];
        sv[1][tid] = (float)y   + fp[HW_ + hw];
      } else {
        const float* fp = f2t + (long)n * 2 * HW_;
        sv[0][tid] = (float)tid + fp[hw];
        sv[1][tid] = (float)y   + fp[HW_ + hw];
      }
    }
    __syncthreads();
    const float* sp = src + fn + (long)c0 * HW_;
    for (int i = tid; i < 16 * 112; i += 256) {
      int c = i / 112, x = i - c * 112;
      sm[c][x] = bilin(sp + (long)c * HW_, sv[0][x], sv[1][x]);
    }
  }
  __syncthreads();
  if (tid < 224) {
    int px = tid >> 1, gg = tid & 1;
    unsigned hh[8], ll[8];
#pragma unroll
    for (int j = 0; j < 8; ++j) {
      float v = sm[gg * 8 + j][px];
      hh[j] = f2bf(v);
      ll[j] = f2bf(v - bf2f((unsigned short)hh[j]));
    }
    long o = ((long)(n * 12 + icb) * PPX_ + (long)(y + 1) * PROW_ + (px + 1)) * 16 + gg * 8;
    uint4 uh, ul;
    uh.x = hh[0] | (hh[1] << 16); uh.y = hh[2] | (hh[3] << 16);
    uh.z = hh[4] | (hh[5] << 16); uh.w = hh[6] | (hh[7] << 16);
    ul.x = ll[0] | (ll[1] << 16); ul.y = ll[2] | (ll[3] << 16);
    ul.z = ll[4] | (ll[5] << 16); ul.w = ll[6] | (ll[7] << 16);
    *(uint4*)(xhi + o) = uh;
    *(uint4*)(xlo + o) = ul;
  }
}

// ---------------------------------------------------------------------------
// pack_w: W (64, IC, 3, 3) fp32 -> MFMA A-fragment order, split hi/lo bf16.
// id -> [mt][tap][icb][lane][r]: oc = mt*32+(lane&31), ic = icb*16+(lane>>5)*8+r.
// ---------------------------------------------------------------------------
__global__ __launch_bounds__(256) void pack_w(
    const float* __restrict__ W, short* __restrict__ whi, short* __restrict__ wlo,
    int ICBC) {
  int id = blockIdx.x * 256 + threadIdx.x;
  int total = 2 * 9 * ICBC * 64 * 8;
  if (id >= total) return;
  int r    = id & 7;
  int lane = (id >> 3) & 63;
  int rest = id >> 9;
  int icb  = rest % ICBC;
  int mtt  = rest / ICBC;
  int tap  = mtt % 9;
  int mt   = mtt / 9;
  int oc = mt * 32 + (lane & 31);
  int ic = icb * 16 + ((lane >> 5) << 3) + r;
  int ky = tap / 3, kx = tap % 3;
  int IC = ICBC * 16;
  float v = W[(((long)oc * IC + ic) * 3 + ky) * 3 + kx];
  unsigned short h = f2bf(v);
  unsigned short l = f2bf(v - bf2f(h));
  whi[id] = (short)h;
  wlo[id] = (short)l;
}

// ---------------------------------------------------------------------------
// conv_mfma_l: 3x3 SAME conv partial, implicit-GEMM split-bf16 MFMA 32x32x16.
// KG == ICBT (NICB = 1): a block reduces exactly ONE icb (16 ic) -> there is
// NO K-loop, hence nothing for the compiler to mis-pipeline (r5/r7/r8 lesson:
// hipcc will not keep global loads in flight across an unrolled loop).
// Structure: one async staging burst via __builtin_amdgcn_global_load_lds
// (x tile 9KB + ALL 36 weight fragments 36KB -> LDS), one barrier, then
// 9 taps x {4 ds_read_b128 + 3 MFMA} entirely LDS-fed. 2 acc chains
// (A: wh*xh; B: wl*xh then wh*xl chained - MFMA same-acc chaining runs at
// full rate). Block = 256 thr (4 waves): wave = (mt = wid&1, row = wid>>1).
// blockIdx.z = n*ICBT + icb -> fp32 partial part[z][64 oc][HW].
// LDS 46KB -> 3 blocks/CU (12 waves/CU); compute phase ~LDS-BW bound.
// ---------------------------------------------------------------------------
template <int ICBT>
__global__ __launch_bounds__(256) void conv_mfma_l(
    const short* __restrict__ xhi, const short* __restrict__ xlo,
    const short* __restrict__ whi, const short* __restrict__ wlo,
    float* __restrict__ part) {
  __shared__ alignas(16) short sx[2 * 4 * 36 * 16];  // [hl][row 4][slot 36][16ic] 9216B
  __shared__ alignas(16) short sw[36 * 512];         // [(mt*9+tap)*2+hl][lane][8] 36864B
  const int tid  = threadIdx.x;
  const int lane = tid & 63;
  const int wid  = tid >> 6;
  const int mt   = wid & 1;
  const int row  = wid >> 1;
  const int g    = (lane >> 5) & 1;
  const int bx   = blockIdx.x * 32;
  const int by2  = blockIdx.y * 2;
  const int z    = blockIdx.z;          // n*ICBT + icb
  const int icb  = z % ICBT;

  // --- staging burst: weights (9 units/wave x 1KB) ---
#pragma unroll
  for (int i = 0; i < 9; ++i) {
    int u = wid + i * 4;                          // 0..35, wave-uniform
    int hl = u & 1, mtt = u / 18, tap = (u >> 1) % 9;
    const short* src = (hl ? wlo : whi)
        + ((long)((mtt * 9 + tap) * ICBT + icb)) * 512 + lane * 8;
    __builtin_amdgcn_global_load_lds(src, &sw[u * 512], 16, 0, 0);
  }
  // --- staging burst: x tile (rows by2..by2+3, cols bx..bx+35, hi+lo) ---
  // chunk c (16B) -> (hl = c/288, r = (c%288)/72, k = c%72); LDS dest = c*16B
  // (linear); global source = slab row base + k*16B (linear in k).
#pragma unroll
  for (int i = 0; i < 3; ++i) {
    int c0 = i * 256 + wid * 64;                  // wave-uniform chunk base
    if (c0 < 576) {
      int c = c0 + lane;
      int hl = c / 288, rem = c - hl * 288, r = rem / 72, k = rem - r * 72;
      const short* src = (hl ? xlo : xhi)
          + ((long)z * PPX_ + (long)(by2 + r) * PROW_ + bx) * 16 + k * 8;
      __builtin_amdgcn_global_load_lds(src, &sx[c0 * 8], 16, 0, 0);
    }
  }
  __syncthreads();   // compiler emits vmcnt(0) drain here

  f32x16 accA, accB;
#pragma unroll
  for (int i = 0; i < 16; ++i) { accA[i] = 0.f; accB[i] = 0.f; }

#pragma unroll
  for (int tap = 0; tap < 9; ++tap) {
    const int dy = tap / 3, dx = tap % 3;
    const short* xb = &sx[(row + dy) * 576 + ((lane & 31) + dx) * 16 + g * 8];
    bf16x8 xh = *(const bf16x8*)xb;
    bf16x8 xl = *(const bf16x8*)(xb + 2304);
    const short* wb = &sw[(mt * 9 + tap) * 1024 + lane * 8];
    bf16x8 wh = *(const bf16x8*)wb;
    bf16x8 wl = *(const bf16x8*)(wb + 512);
    accA = __builtin_amdgcn_mfma_f32_32x32x16_bf16(wh, xh, accA, 0, 0, 0);
    accB = __builtin_amdgcn_mfma_f32_32x32x16_bf16(wl, xh, accB, 0, 0, 0);
    accB = __builtin_amdgcn_mfma_f32_32x32x16_bf16(wh, xl, accB, 0, 0, 0);
  }

  int pxg = bx + (lane & 31);
  int y   = by2 + row;
  if (pxg < W_) {
    long base = (long)z * 64 * HW_ + (long)y * W_ + pxg;
#pragma unroll
    for (int r = 0; r < 16; ++r) {
      int oc = mt * 32 + (r & 3) + 8 * (r >> 2) + 4 * g;
      part[base + (long)oc * HW_] = accA[r] + accB[r];
    }
  }
}

// ---------------------------------------------------------------------------
// combine1: h1 = lrelu(sum_kg part + bias) -> packed padded hi/lo (conv2 in).
// KG partials. Block = (n, icb 0..3, row y).
// ---------------------------------------------------------------------------
template <int KG>
__global__ __launch_bounds__(256) void combine1(
    const float* __restrict__ part, const float* __restrict__ bias,
    short* __restrict__ ohi, short* __restrict__ olo) {
  __shared__ float sm[16][113];
  int bid = blockIdx.x;
  int y   = bid % H_;
  int icb = (bid / H_) % 4;
  int n   = bid / (H_ * 4);
  int tid = threadIdx.x;
  for (int i = tid; i < 16 * 112; i += 256) {
    int c = i / 112, x = i - c * 112;
    int oc = icb * 16 + c;
    long hw = (long)y * W_ + x;
    float v = bias[oc];
#pragma unroll
    for (int k = 0; k < KG; ++k)
      v += part[((long)(n * KG + k) * 64 + oc) * HW_ + hw];
    v = v > 0.f ? v : v * SLOPE_;
    sm[c][x] = v;
  }
  __syncthreads();
  if (tid < 224) {
    int px = tid >> 1, gg = tid & 1;
    unsigned hh[8], ll[8];
#pragma unroll
    for (int j = 0; j < 8; ++j) {
      float v = sm[gg * 8 + j][px];
      hh[j] = f2bf(v);
      ll[j] = f2bf(v - bf2f((unsigned short)hh[j]));
    }
    long o = ((long)(n * 4 + icb) * PPX_ + (long)(y + 1) * PROW_ + (px + 1)) * 16 + gg * 8;
    uint4 uh, ul;
    uh.x = hh[0] | (hh[1] << 16); uh.y = hh[2] | (hh[3] << 16);
    uh.z = hh[4] | (hh[5] << 16); uh.w = hh[6] | (hh[7] << 16);
    ul.x = ll[0] | (ll[1] << 16); ul.y = ll[2] | (ll[3] << 16);
    ul.z = ll[4] | (ll[5] << 16); ul.w = ll[6] | (ll[7] << 16);
    *(uint4*)(ohi + o) = uh;
    *(uint4*)(olo + o) = ul;
  }
}

// ---------------------------------------------------------------------------
// combine2: out[t] += sum_kg part + bias (residual already in out[t]).
// ---------------------------------------------------------------------------
template <int KG>
__global__ __launch_bounds__(256) void combine2(
    const float* __restrict__ part, const float* __restrict__ bias,
    float* __restrict__ out_t) {
  int id = blockIdx.x * 256 + threadIdx.x;
  if (id >= N_ * C_ * HW_) return;
  int hw = id % HW_;
  int oc = (id / HW_) % C_;
  int n  = id / (HW_ * C_);
  long o = (long)n * T_ * C_ * HW_ + (long)oc * HW_ + hw;
  float v = bias[oc] + out_t[o];
#pragma unroll
  for (int k = 0; k < KG; ++k)
    v += part[((long)(n * KG + k) * 64 + oc) * HW_ + hw];
  out_t[o] = v;
}

// ---------------------------------------------------------------------------
// Host-side orchestration
// ---------------------------------------------------------------------------
constexpr int KG1 = 12;  // conv1: one icb per block (5376 blocks)
constexpr int KG2 = 4;   // conv2: one icb per block (1792 blocks)

struct Bufs {
  float* f2t; float* part;
  short *xhi, *xlo, *h1hi, *h1lo, *w1hi, *w1lo, *w2hi, *w2lo;
};

static void run_step(float* out, const float* flows, int t, bool fwd, int i,
                     const float* b1, const float* b2, const Bufs& B,
                     hipStream_t stream) {
  const float* curr = out + (long)t * C_ * HW_;
  const float* p1 = nullptr;
  const float* p2 = nullptr;
  const float* f1 = nullptr;
  const float* f2 = nullptr;
  if (fwd) {
    if (t >= 1) { p1 = out + (long)(t - 1) * C_ * HW_; f1 = flows + (long)(t - 1) * 2 * HW_; }
    if (t >= 2) { p2 = out + (long)(t - 2) * C_ * HW_; f2 = flows + (long)(t - 2) * 2 * HW_; }
  } else {
    if (i >= 1) { p1 = out + (long)(t + 1) * C_ * HW_; f1 = flows + (long)(t + 1) * 2 * HW_; }
    if (i >= 2) { p2 = out + (long)(t + 2) * C_ * HW_; f2 = flows + (long)(t + 2) * 2 * HW_; }
  }

  if (p2) {
    int nb = (N_ * HW_ + 255) / 256;
    f2tot_kernel<<<nb, 256, 0, stream>>>(f1, f2, B.f2t);
  }
  warp_pack<<<N_ * 12 * H_, 256, 0, stream>>>(curr, p1, p2, f1, B.f2t, B.xhi, B.xlo);
  conv_mfma_l<12><<<dim3(4, 56, N_ * KG1), 256, 0, stream>>>(
      B.xhi, B.xlo, B.w1hi, B.w1lo, B.part);
  combine1<KG1><<<N_ * 4 * H_, 256, 0, stream>>>(B.part, b1, B.h1hi, B.h1lo);
  conv_mfma_l<4><<<dim3(4, 56, N_ * KG2), 256, 0, stream>>>(
      B.h1hi, B.h1lo, B.w2hi, B.w2lo, B.part);
  combine2<KG2><<<(N_ * C_ * HW_ + 255) / 256, 256, 0, stream>>>(
      B.part, b2, out + (long)t * C_ * HW_);
}

extern "C" void kernel_launch(void* const* d_in, const int* in_sizes, int n_in,
                              void* d_out, int out_size, void* d_ws, size_t ws_size,
                              hipStream_t stream) {
  const float* feats = (const float*)d_in[0];
  const float* fflow = (const float*)d_in[1];
  const float* bflow = (const float*)d_in[2];
  const float* W1 = (const float*)d_in[3];
  const float* b1 = (const float*)d_in[4];
  const float* W2 = (const float*)d_in[5];
  const float* b2 = (const float*)d_in[6];
  float* out = (float*)d_out;

  char* p = (char*)d_ws;
  auto carve = [&](size_t bytes) {
    void* r = (void*)p;
    p += (bytes + 255) & ~(size_t)255;
    return r;
  };
  Bufs B;
  size_t xpack_sh  = (size_t)N_ * 12 * PPX_ * 16;
  size_t h1pack_sh = (size_t)N_ * 4 * PPX_ * 16;
  B.f2t  = (float*)carve(sizeof(float) * N_ * 2 * HW_);
  B.part = (float*)carve(sizeof(float) * (size_t)KG1 * N_ * 64 * HW_);
  B.xhi  = (short*)carve(2 * xpack_sh);
  B.xlo  = (short*)carve(2 * xpack_sh);
  B.h1hi = (short*)carve(2 * h1pack_sh);
  B.h1lo = (short*)carve(2 * h1pack_sh);
  B.w1hi = (short*)carve(2 * (size_t)(2 * 9 * 12 * 64 * 8));
  B.w1lo = (short*)carve(2 * (size_t)(2 * 9 * 12 * 64 * 8));
  B.w2hi = (short*)carve(2 * (size_t)(2 * 9 * 4 * 64 * 8));
  B.w2lo = (short*)carve(2 * (size_t)(2 * 9 * 4 * 64 * 8));

  // Zero packed buffers once per launch (zeros the conv padding halos).
  hipMemsetAsync(B.xhi, 0, 2 * xpack_sh, stream);
  hipMemsetAsync(B.xlo, 0, 2 * xpack_sh, stream);
  hipMemsetAsync(B.h1hi, 0, 2 * h1pack_sh, stream);
  hipMemsetAsync(B.h1lo, 0, 2 * h1pack_sh, stream);

  // Weight fragments (hi/lo split), once per launch.
  pack_w<<<(2 * 9 * 12 * 64 * 8 + 255) / 256, 256, 0, stream>>>(W1, B.w1hi, B.w1lo, 12);
  pack_w<<<(2 * 9 * 4 * 64 * 8 + 255) / 256, 256, 0, stream>>>(W2, B.w2hi, B.w2lo, 4);

  // Seed the working feats (in d_out) with the input feats.
  hipMemcpyAsync(out, feats, sizeof(float) * (size_t)N_ * T_ * C_ * HW_,
                 hipMemcpyDeviceToDevice, stream);

  for (int t = 0; t < T_; ++t)
    run_step(out, fflow, t, true, t, b1, b2, B, stream);
  for (int i = 0; i < T_; ++i) {
    int t = T_ - 1 - i;
    run_step(out, bflow, t, false, i, b1, b2, B, stream);
  }
}

// Round 13
// 1900.400 us; speedup vs baseline: 1.1556x; 1.0735x over previous
//
#include <hip/hip_runtime.h>

// Problem constants (fixed by reference)
constexpr int N_ = 2, T_ = 12, C_ = 64, H_ = 112, W_ = 112;
constexpr int HW_ = H_ * W_;
constexpr float SLOPE_ = 0.1f;
// Padded packed activation layout: rows -1..112 (114), cols -1..129 (131)
constexpr int PROW_ = 131;
constexpr int PNROW_ = 114;
constexpr int PPX_ = PROW_ * PNROW_;

typedef short bf16x8 __attribute__((ext_vector_type(8)));
typedef float f32x16 __attribute__((ext_vector_type(16)));

__device__ __forceinline__ unsigned short f2bf(float f) {
  unsigned u = __float_as_uint(f);
  unsigned r = (u + 0x7fffu + ((u >> 16) & 1u)) >> 16;
  return (unsigned short)r;
}
__device__ __forceinline__ float bf2f(unsigned short h) {
  return __uint_as_float(((unsigned)h) << 16);
}

// ---------------------------------------------------------------------------
// Bilinear sample with zero padding outside (matches reference flow_warp).
// ---------------------------------------------------------------------------
__device__ __forceinline__ float samp_one(const float* __restrict__ img, int y, int x) {
  if ((unsigned)x < (unsigned)W_ && (unsigned)y < (unsigned)H_)
    return img[y * W_ + x];
  return 0.f;
}

__device__ __forceinline__ float bilin(const float* __restrict__ img, float vx, float vy) {
  float x0f = floorf(vx), y0f = floorf(vy);
  int x0 = (int)x0f, y0 = (int)y0f;
  float wx = vx - x0f, wy = vy - y0f;
  float g00 = samp_one(img, y0,     x0);
  float g01 = samp_one(img, y0,     x0 + 1);
  float g10 = samp_one(img, y0 + 1, x0);
  float g11 = samp_one(img, y0 + 1, x0 + 1);
  return g00 * (1.f - wx) * (1.f - wy)
       + g01 * wx * (1.f - wy)
       + g10 * (1.f - wx) * wy
       + g11 * wx * wy;
}

// ---------------------------------------------------------------------------
// halo_zero: zero only the pad ring of the 4 packed buffers (replaces 4 full
// memsets). Ring per slab: rows {0,113} full + rows 1..112 x cols {0,113..130}.
// ---------------------------------------------------------------------------
__global__ __launch_bounds__(256) void halo_zero(
    short* __restrict__ xhi, short* __restrict__ xlo,
    short* __restrict__ h1hi, short* __restrict__ h1lo) {
  constexpr int PXH = 2 * PROW_ + 112 * 19;   // 2390 halo pixels per slab
  int id = blockIdx.x * 256 + threadIdx.x;
  int total = (24 + 8) * 2 * PXH;             // 24 x-slabs + 8 h1-slabs, hi+lo
  if (id >= total) return;
  int p  = id % PXH;
  int sb = id / PXH;
  int row, col;
  if (p < 2 * PROW_) { row = (p < PROW_) ? 0 : PNROW_ - 1; col = p % PROW_; }
  else { int q = p - 2 * PROW_; row = 1 + q / 19; int c19 = q % 19; col = c19 ? 112 + c19 : 0; }
  short* base;
  if (sb < 48) { base = (sb & 1) ? xlo : xhi; base += ((long)(sb >> 1)) * PPX_ * 16; }
  else { int s = sb - 48; base = (s & 1) ? h1lo : h1hi; base += ((long)(s >> 1)) * PPX_ * 16; }
  short* q16 = base + ((long)row * PROW_ + col) * 16;
  *(uint4*)q16 = uint4{0, 0, 0, 0};
  *(uint4*)(q16 + 8) = uint4{0, 0, 0, 0};
}

// ---------------------------------------------------------------------------
// warp_pack: fused build_aggr + f2_tot + pack. Block = (n, icb 0..11, row y).
// slot = icb/4: 0=curr copy, 1=warp(p1,f1), 2=warp(p2, f1+warp(f2,f1));
// falls back to curr when p1/p2 null. Output padded packed hi/lo bf16
// [n][12][PPX][16ic].
// ---------------------------------------------------------------------------
__global__ __launch_bounds__(256) void warp_pack(
    const float* __restrict__ curr,
    const float* __restrict__ p1,
    const float* __restrict__ p2,
    const float* __restrict__ f1,
    const float* __restrict__ f2,
    short* __restrict__ xhi, short* __restrict__ xlo) {
  __shared__ float sm[16][113];
  __shared__ float sv[2][112];
  int bid = blockIdx.x;
  int y   = bid % H_;
  int icb = (bid / H_) % 12;
  int n   = bid / (H_ * 12);
  int tid = threadIdx.x;
  int slot = icb >> 2;
  int c0   = (icb & 3) * 16;
  long fn = (long)n * T_ * C_ * HW_;

  const float* src = nullptr;
  if (slot == 1 && p1) src = p1;
  if (slot == 2 && p2) src = p2;

  if (src == nullptr) {
    const float* cp = curr + fn + (long)c0 * HW_ + (long)y * W_;
    for (int i = tid; i < 16 * 112; i += 256) {
      int c = i / 112, x = i - c * 112;
      sm[c][x] = cp[(long)c * HW_ + x];
    }
  } else {
    if (tid < 112) {
      long hw = (long)y * W_ + tid;
      const float* f1n = f1 + (long)n * T_ * 2 * HW_;
      if (slot == 1) {
        sv[0][tid] = (float)tid + f1n[hw];
        sv[1][tid] = (float)y   + f1n[HW_ + hw];
      } else {
        const float* f2n = f2 + (long)n * T_ * 2 * HW_;
        float vx = (float)tid + f1n[hw];
        float vy = (float)y   + f1n[HW_ + hw];
        float wfx = bilin(f2n,       vx, vy);
        float wfy = bilin(f2n + HW_, vx, vy);
        sv[0][tid] = vx + wfx;   // x + f2_tot.x
        sv[1][tid] = vy + wfy;   // y + f2_tot.y
      }
    }
    __syncthreads();
    const float* sp = src + fn + (long)c0 * HW_;
    for (int i = tid; i < 16 * 112; i += 256) {
      int c = i / 112, x = i - c * 112;
      sm[c][x] = bilin(sp + (long)c * HW_, sv[0][x], sv[1][x]);
    }
  }
  __syncthreads();
  if (tid < 224) {
    int px = tid >> 1, gg = tid & 1;
    unsigned hh[8], ll[8];
#pragma unroll
    for (int j = 0; j < 8; ++j) {
      float v = sm[gg * 8 + j][px];
      hh[j] = f2bf(v);
      ll[j] = f2bf(v - bf2f((unsigned short)hh[j]));
    }
    long o = ((long)(n * 12 + icb) * PPX_ + (long)(y + 1) * PROW_ + (px + 1)) * 16 + gg * 8;
    uint4 uh, ul;
    uh.x = hh[0] | (hh[1] << 16); uh.y = hh[2] | (hh[3] << 16);
    uh.z = hh[4] | (hh[5] << 16); uh.w = hh[6] | (hh[7] << 16);
    ul.x = ll[0] | (ll[1] << 16); ul.y = ll[2] | (ll[3] << 16);
    ul.z = ll[4] | (ll[5] << 16); ul.w = ll[6] | (ll[7] << 16);
    *(uint4*)(xhi + o) = uh;
    *(uint4*)(xlo + o) = ul;
  }
}

// ---------------------------------------------------------------------------
// pack_w: W (64, IC, 3, 3) fp32 -> MFMA A-fragment order, split hi/lo bf16.
// id -> [mt][tap][icb][lane][r]: oc = mt*32+(lane&31), ic = icb*16+(lane>>5)*8+r.
// ---------------------------------------------------------------------------
__global__ __launch_bounds__(256) void pack_w(
    const float* __restrict__ W, short* __restrict__ whi, short* __restrict__ wlo,
    int ICBC) {
  int id = blockIdx.x * 256 + threadIdx.x;
  int total = 2 * 9 * ICBC * 64 * 8;
  if (id >= total) return;
  int r    = id & 7;
  int lane = (id >> 3) & 63;
  int rest = id >> 9;
  int icb  = rest % ICBC;
  int mtt  = rest / ICBC;
  int tap  = mtt % 9;
  int mt   = mtt / 9;
  int oc = mt * 32 + (lane & 31);
  int ic = icb * 16 + ((lane >> 5) << 3) + r;
  int ky = tap / 3, kx = tap % 3;
  int IC = ICBC * 16;
  float v = W[(((long)oc * IC + ic) * 3 + ky) * 3 + kx];
  unsigned short h = f2bf(v);
  unsigned short l = f2bf(v - bf2f(h));
  whi[id] = (short)h;
  wlo[id] = (short)l;
}

// ---------------------------------------------------------------------------
// conv_body: 3x3 SAME conv partial, implicit-GEMM split-bf16 MFMA 32x32x16.
// __device__ template called from CONCRETE __global__ kernels (r10 lesson:
// template __global__ + __launch_bounds__ min-occupancy dropped the
// instantiation -> undefined __device_stub__ at dlopen; concrete kernels
// cannot lose their stubs). Plain __launch_bounds__(256): no feasibility
// cliff; LDS 27.6KB caps at 5 blocks/CU, VGPR expected ~80-100.
// x-only LDS staging (global_load_lds one burst, one barrier); weights read
// per tap from fragment-ordered global: block-uniform address, L2-resident
// (1.7MB), L1-reused across co-resident blocks. Block = 256 thr (4 waves):
// wave = (mt = wid&1, row = wid>>1). z = n*KG + kg; kg reduces NICB icbs.
// 2 acc chains: accA = wh*xh; accB = wl*xh + wh*xl.
// ---------------------------------------------------------------------------
template <int ICBT, int KG>
__device__ __forceinline__ void conv_body(
    const short* __restrict__ xhi, const short* __restrict__ xlo,
    const short* __restrict__ whi, const short* __restrict__ wlo,
    float* __restrict__ part, short* __restrict__ sx) {
  constexpr int NICB  = ICBT / KG;
  constexpr int UNITS = NICB * 9;                 // 1KB staging units
  const int tid  = threadIdx.x;
  const int lane = tid & 63;
  const int wid  = tid >> 6;
  const int mt   = wid & 1;
  const int row  = wid >> 1;
  const int g    = (lane >> 5) & 1;
  const int bx   = blockIdx.x * 32;
  const int by2  = blockIdx.y * 2;
  const int z    = blockIdx.z;
  const int kg   = z % KG;
  const int n    = z / KG;
  const int icb0 = kg * NICB;

  // Staging burst: chunk c (16B) -> LDS c*16B (linear, wave-uniform base +
  // lane*16); global source per-lane: c = [ii][hl][row r][k], src = slab row
  // base + k*16B.
#pragma unroll
  for (int i = 0; i < (UNITS + 3) / 4; ++i) {
    int u = wid + i * 4;                          // wave-uniform
    if (u < UNITS) {
      int c = u * 64 + lane;
      int ii  = c / 576;
      int rem = c - ii * 576;
      int hl  = rem / 288;
      int rem2 = rem - hl * 288;
      int r = rem2 / 72, k = rem2 - r * 72;
      const short* src = (hl ? xlo : xhi)
          + ((long)(n * ICBT + icb0 + ii) * PPX_ + (long)(by2 + r) * PROW_ + bx) * 16 + k * 8;
      __builtin_amdgcn_global_load_lds(src, &sx[c * 8], 16, 0, 0);
    }
  }
  __syncthreads();

  f32x16 accA, accB;
#pragma unroll
  for (int i = 0; i < 16; ++i) { accA[i] = 0.f; accB[i] = 0.f; }

#pragma unroll
  for (int ii = 0; ii < NICB; ++ii) {
#pragma unroll
    for (int tap = 0; tap < 9; ++tap) {
      const int dy = tap / 3, dx = tap % 3;
      const short* xb = &sx[ii * 4608 + (row + dy) * 576 + ((lane & 31) + dx) * 16 + g * 8];
      bf16x8 xh = *(const bf16x8*)xb;
      bf16x8 xl = *(const bf16x8*)(xb + 2304);
      long wi = ((long)((mt * 9 + tap) * ICBT + icb0 + ii)) * 512 + lane * 8;
      bf16x8 wh = *(const bf16x8*)(whi + wi);
      bf16x8 wl = *(const bf16x8*)(wlo + wi);
      accA = __builtin_amdgcn_mfma_f32_32x32x16_bf16(wh, xh, accA, 0, 0, 0);
      accB = __builtin_amdgcn_mfma_f32_32x32x16_bf16(wl, xh, accB, 0, 0, 0);
      accB = __builtin_amdgcn_mfma_f32_32x32x16_bf16(wh, xl, accB, 0, 0, 0);
    }
  }

  int pxg = bx + (lane & 31);
  int y   = by2 + row;
  if (pxg < W_) {
    long base = (long)z * 64 * HW_ + (long)y * W_ + pxg;
#pragma unroll
    for (int r = 0; r < 16; ++r) {
      int oc = mt * 32 + (r & 3) + 8 * (r >> 2) + 4 * g;
      part[base + (long)oc * HW_] = accA[r] + accB[r];
    }
  }
}

__global__ __launch_bounds__(256) void conv1_mfma(
    const short* __restrict__ xhi, const short* __restrict__ xlo,
    const short* __restrict__ whi, const short* __restrict__ wlo,
    float* __restrict__ part) {
  __shared__ alignas(16) short sx[3 * 4608];   // NICB=3 -> 27648 B
  conv_body<12, 4>(xhi, xlo, whi, wlo, part, sx);
}

__global__ __launch_bounds__(256) void conv2_mfma(
    const short* __restrict__ xhi, const short* __restrict__ xlo,
    const short* __restrict__ whi, const short* __restrict__ wlo,
    float* __restrict__ part) {
  __shared__ alignas(16) short sx[1 * 4608];   // NICB=1 -> 9216 B
  conv_body<4, 4>(xhi, xlo, whi, wlo, part, sx);
}

// ---------------------------------------------------------------------------
// combine1: h1 = lrelu(sum_kg part + bias) -> packed padded hi/lo (conv2 in).
// ---------------------------------------------------------------------------
template <int KG>
__global__ __launch_bounds__(256) void combine1(
    const float* __restrict__ part, const float* __restrict__ bias,
    short* __restrict__ ohi, short* __restrict__ olo) {
  __shared__ float sm[16][113];
  int bid = blockIdx.x;
  int y   = bid % H_;
  int icb = (bid / H_) % 4;
  int n   = bid / (H_ * 4);
  int tid = threadIdx.x;
  for (int i = tid; i < 16 * 112; i += 256) {
    int c = i / 112, x = i - c * 112;
    int oc = icb * 16 + c;
    long hw = (long)y * W_ + x;
    float v = bias[oc];
#pragma unroll
    for (int k = 0; k < KG; ++k)
      v += part[((long)(n * KG + k) * 64 + oc) * HW_ + hw];
    v = v > 0.f ? v : v * SLOPE_;
    sm[c][x] = v;
  }
  __syncthreads();
  if (tid < 224) {
    int px = tid >> 1, gg = tid & 1;
    unsigned hh[8], ll[8];
#pragma unroll
    for (int j = 0; j < 8; ++j) {
      float v = sm[gg * 8 + j][px];
      hh[j] = f2bf(v);
      ll[j] = f2bf(v - bf2f((unsigned short)hh[j]));
    }
    long o = ((long)(n * 4 + icb) * PPX_ + (long)(y + 1) * PROW_ + (px + 1)) * 16 + gg * 8;
    uint4 uh, ul;
    uh.x = hh[0] | (hh[1] << 16); uh.y = hh[2] | (hh[3] << 16);
    uh.z = hh[4] | (hh[5] << 16); uh.w = hh[6] | (hh[7] << 16);
    ul.x = ll[0] | (ll[1] << 16); ul.y = ll[2] | (ll[3] << 16);
    ul.z = ll[4] | (ll[5] << 16); ul.w = ll[6] | (ll[7] << 16);
    *(uint4*)(ohi + o) = uh;
    *(uint4*)(olo + o) = ul;
  }
}

// ---------------------------------------------------------------------------
// combine2: out[t] += sum_kg part + bias (residual already in out[t]).
// ---------------------------------------------------------------------------
template <int KG>
__global__ __launch_bounds__(256) void combine2(
    const float* __restrict__ part, const float* __restrict__ bias,
    float* __restrict__ out_t) {
  int id = blockIdx.x * 256 + threadIdx.x;
  if (id >= N_ * C_ * HW_) return;
  int hw = id % HW_;
  int oc = (id / HW_) % C_;
  int n  = id / (HW_ * C_);
  long o = (long)n * T_ * C_ * HW_ + (long)oc * HW_ + hw;
  float v = bias[oc] + out_t[o];
#pragma unroll
  for (int k = 0; k < KG; ++k)
    v += part[((long)(n * KG + k) * 64 + oc) * HW_ + hw];
  out_t[o] = v;
}

// ---------------------------------------------------------------------------
// Host-side orchestration
// ---------------------------------------------------------------------------
constexpr int KG1 = 4;   // conv1 K-split: NICB=3, 1792 blocks, part 26MB
constexpr int KG2 = 4;   // conv2 K-split: NICB=1, 1792 blocks

struct Bufs {
  float* part;
  short *xhi, *xlo, *h1hi, *h1lo, *w1hi, *w1lo, *w2hi, *w2lo;
};

static void run_step(float* out, const float* flows, int t, bool fwd, int i,
                     const float* b1, const float* b2, const Bufs& B,
                     hipStream_t stream) {
  const float* curr = out + (long)t * C_ * HW_;
  const float* p1 = nullptr;
  const float* p2 = nullptr;
  const float* f1 = nullptr;
  const float* f2 = nullptr;
  if (fwd) {
    if (t >= 1) { p1 = out + (long)(t - 1) * C_ * HW_; f1 = flows + (long)(t - 1) * 2 * HW_; }
    if (t >= 2) { p2 = out + (long)(t - 2) * C_ * HW_; f2 = flows + (long)(t - 2) * 2 * HW_; }
  } else {
    if (i >= 1) { p1 = out + (long)(t + 1) * C_ * HW_; f1 = flows + (long)(t + 1) * 2 * HW_; }
    if (i >= 2) { p2 = out + (long)(t + 2) * C_ * HW_; f2 = flows + (long)(t + 2) * 2 * HW_; }
  }

  warp_pack<<<N_ * 12 * H_, 256, 0, stream>>>(curr, p1, p2, f1, f2, B.xhi, B.xlo);
  conv1_mfma<<<dim3(4, 56, N_ * KG1), 256, 0, stream>>>(
      B.xhi, B.xlo, B.w1hi, B.w1lo, B.part);
  combine1<KG1><<<N_ * 4 * H_, 256, 0, stream>>>(B.part, b1, B.h1hi, B.h1lo);
  conv2_mfma<<<dim3(4, 56, N_ * KG2), 256, 0, stream>>>(
      B.h1hi, B.h1lo, B.w2hi, B.w2lo, B.part);
  combine2<KG2><<<(N_ * C_ * HW_ + 255) / 256, 256, 0, stream>>>(
      B.part, b2, out + (long)t * C_ * HW_);
}

extern "C" void kernel_launch(void* const* d_in, const int* in_sizes, int n_in,
                              void* d_out, int out_size, void* d_ws, size_t ws_size,
                              hipStream_t stream) {
  const float* feats = (const float*)d_in[0];
  const float* fflow = (const float*)d_in[1];
  const float* bflow = (const float*)d_in[2];
  const float* W1 = (const float*)d_in[3];
  const float* b1 = (const float*)d_in[4];
  const float* W2 = (const float*)d_in[5];
  const float* b2 = (const float*)d_in[6];
  float* out = (float*)d_out;

  char* p = (char*)d_ws;
  auto carve = [&](size_t bytes) {
    void* r = (void*)p;
    p += (bytes + 255) & ~(size_t)255;
    return r;
  };
  Bufs B;
  size_t xpack_sh  = (size_t)N_ * 12 * PPX_ * 16;
  size_t h1pack_sh = (size_t)N_ * 4 * PPX_ * 16;
  B.part = (float*)carve(sizeof(float) * (size_t)KG1 * N_ * 64 * HW_);
  B.xhi  = (short*)carve(2 * xpack_sh);
  B.xlo  = (short*)carve(2 * xpack_sh);
  B.h1hi = (short*)carve(2 * h1pack_sh);
  B.h1lo = (short*)carve(2 * h1pack_sh);
  B.w1hi = (short*)carve(2 * (size_t)(2 * 9 * 12 * 64 * 8));
  B.w1lo = (short*)carve(2 * (size_t)(2 * 9 * 12 * 64 * 8));
  B.w2hi = (short*)carve(2 * (size_t)(2 * 9 * 4 * 64 * 8));
  B.w2lo = (short*)carve(2 * (size_t)(2 * 9 * 4 * 64 * 8));

  // Zero only the pad rings (interior fully rewritten every step).
  {
    constexpr int PXH = 2 * PROW_ + 112 * 19;
    int total = (24 + 8) * 2 * PXH;
    halo_zero<<<(total + 255) / 256, 256, 0, stream>>>(B.xhi, B.xlo, B.h1hi, B.h1lo);
  }

  // Weight fragments (hi/lo split), once per launch.
  pack_w<<<(2 * 9 * 12 * 64 * 8 + 255) / 256, 256, 0, stream>>>(W1, B.w1hi, B.w1lo, 12);
  pack_w<<<(2 * 9 * 4 * 64 * 8 + 255) / 256, 256, 0, stream>>>(W2, B.w2hi, B.w2lo, 4);

  // Seed the working feats (in d_out) with the input feats.
  hipMemcpyAsync(out, feats, sizeof(float) * (size_t)N_ * T_ * C_ * HW_,
                 hipMemcpyDeviceToDevice, stream);

  for (int t = 0; t < T_; ++t)
    run_step(out, fflow, t, true, t, b1, b2, B, stream);
  for (int i = 0; i < T_; ++i) {
    int t = T_ - 1 - i;
    run_step(out, bflow, t, false, i, b1, b2, B, stream);
  }
}

// Round 16
// 1889.199 us; speedup vs baseline: 1.1624x; 1.0059x over previous
//
#include <hip/hip_runtime.h>

// Problem constants (fixed by reference)
constexpr int N_ = 2, T_ = 12, C_ = 64, H_ = 112, W_ = 112;
constexpr int HW_ = H_ * W_;
constexpr float SLOPE_ = 0.1f;
// Padded packed activation layout: rows -1..112 (114), cols -1..129 (131)
constexpr int PROW_ = 131;
constexpr int PNROW_ = 114;
constexpr int PPX_ = PROW_ * PNROW_;

typedef short bf16x8 __attribute__((ext_vector_type(8)));
typedef float f32x16 __attribute__((ext_vector_type(16)));

__device__ __forceinline__ unsigned short f2bf(float f) {
  unsigned u = __float_as_uint(f);
  unsigned r = (u + 0x7fffu + ((u >> 16) & 1u)) >> 16;
  return (unsigned short)r;
}
__device__ __forceinline__ float bf2f(unsigned short h) {
  return __uint_as_float(((unsigned)h) << 16);
}

// ---------------------------------------------------------------------------
// Bilinear sample with zero padding outside (matches reference flow_warp).
// ---------------------------------------------------------------------------
__device__ __forceinline__ float samp_one(const float* __restrict__ img, int y, int x) {
  if ((unsigned)x < (unsigned)W_ && (unsigned)y < (unsigned)H_)
    return img[y * W_ + x];
  return 0.f;
}

__device__ __forceinline__ float bilin(const float* __restrict__ img, float vx, float vy) {
  float x0f = floorf(vx), y0f = floorf(vy);
  int x0 = (int)x0f, y0 = (int)y0f;
  float wx = vx - x0f, wy = vy - y0f;
  float g00 = samp_one(img, y0,     x0);
  float g01 = samp_one(img, y0,     x0 + 1);
  float g10 = samp_one(img, y0 + 1, x0);
  float g11 = samp_one(img, y0 + 1, x0 + 1);
  return g00 * (1.f - wx) * (1.f - wy)
       + g01 * wx * (1.f - wy)
       + g10 * (1.f - wx) * wy
       + g11 * wx * wy;
}

// ---------------------------------------------------------------------------
// halo_zero: zero only the pad ring of the 4 packed buffers.
// ---------------------------------------------------------------------------
__global__ __launch_bounds__(256) void halo_zero(
    short* __restrict__ xhi, short* __restrict__ xlo,
    short* __restrict__ h1hi, short* __restrict__ h1lo) {
  constexpr int PXH = 2 * PROW_ + 112 * 19;   // 2390 halo pixels per slab
  int id = blockIdx.x * 256 + threadIdx.x;
  int total = (24 + 8) * 2 * PXH;
  if (id >= total) return;
  int p  = id % PXH;
  int sb = id / PXH;
  int row, col;
  if (p < 2 * PROW_) { row = (p < PROW_) ? 0 : PNROW_ - 1; col = p % PROW_; }
  else { int q = p - 2 * PROW_; row = 1 + q / 19; int c19 = q % 19; col = c19 ? 112 + c19 : 0; }
  short* base;
  if (sb < 48) { base = (sb & 1) ? xlo : xhi; base += ((long)(sb >> 1)) * PPX_ * 16; }
  else { int s = sb - 48; base = (s & 1) ? h1lo : h1hi; base += ((long)(s >> 1)) * PPX_ * 16; }
  short* q16 = base + ((long)row * PROW_ + col) * 16;
  *(uint4*)q16 = uint4{0, 0, 0, 0};
  *(uint4*)(q16 + 8) = uint4{0, 0, 0, 0};
}

// ---------------------------------------------------------------------------
// warp_pack: fused build_aggr + f2_tot + pack. Block = (n, icb 0..11, row y).
// ---------------------------------------------------------------------------
__global__ __launch_bounds__(256) void warp_pack(
    const float* __restrict__ curr,
    const float* __restrict__ p1,
    const float* __restrict__ p2,
    const float* __restrict__ f1,
    const float* __restrict__ f2,
    short* __restrict__ xhi, short* __restrict__ xlo) {
  __shared__ float sm[16][113];
  __shared__ float sv[2][112];
  int bid = blockIdx.x;
  int y   = bid % H_;
  int icb = (bid / H_) % 12;
  int n   = bid / (H_ * 12);
  int tid = threadIdx.x;
  int slot = icb >> 2;
  int c0   = (icb & 3) * 16;
  long fn = (long)n * T_ * C_ * HW_;

  const float* src = nullptr;
  if (slot == 1 && p1) src = p1;
  if (slot == 2 && p2) src = p2;

  if (src == nullptr) {
    const float* cp = curr + fn + (long)c0 * HW_ + (long)y * W_;
    for (int i = tid; i < 16 * 112; i += 256) {
      int c = i / 112, x = i - c * 112;
      sm[c][x] = cp[(long)c * HW_ + x];
    }
  } else {
    if (tid < 112) {
      long hw = (long)y * W_ + tid;
      const float* f1n = f1 + (long)n * T_ * 2 * HW_;
      if (slot == 1) {
        sv[0][tid] = (float)tid + f1n[hw];
        sv[1][tid] = (float)y   + f1n[HW_ + hw];
      } else {
        const float* f2n = f2 + (long)n * T_ * 2 * HW_;
        float vx = (float)tid + f1n[hw];
        float vy = (float)y   + f1n[HW_ + hw];
        float wfx = bilin(f2n,       vx, vy);
        float wfy = bilin(f2n + HW_, vx, vy);
        sv[0][tid] = vx + wfx;   // x + f2_tot.x
        sv[1][tid] = vy + wfy;   // y + f2_tot.y
      }
    }
    __syncthreads();
    const float* sp = src + fn + (long)c0 * HW_;
    for (int i = tid; i < 16 * 112; i += 256) {
      int c = i / 112, x = i - c * 112;
      sm[c][x] = bilin(sp + (long)c * HW_, sv[0][x], sv[1][x]);
    }
  }
  __syncthreads();
  if (tid < 224) {
    int px = tid >> 1, gg = tid & 1;
    unsigned hh[8], ll[8];
#pragma unroll
    for (int j = 0; j < 8; ++j) {
      float v = sm[gg * 8 + j][px];
      hh[j] = f2bf(v);
      ll[j] = f2bf(v - bf2f((unsigned short)hh[j]));
    }
    long o = ((long)(n * 12 + icb) * PPX_ + (long)(y + 1) * PROW_ + (px + 1)) * 16 + gg * 8;
    uint4 uh, ul;
    uh.x = hh[0] | (hh[1] << 16); uh.y = hh[2] | (hh[3] << 16);
    uh.z = hh[4] | (hh[5] << 16); uh.w = hh[6] | (hh[7] << 16);
    ul.x = ll[0] | (ll[1] << 16); ul.y = ll[2] | (ll[3] << 16);
    ul.z = ll[4] | (ll[5] << 16); ul.w = ll[6] | (ll[7] << 16);
    *(uint4*)(xhi + o) = uh;
    *(uint4*)(xlo + o) = ul;
  }
}

// ---------------------------------------------------------------------------
// pack_w: W (64, IC, 3, 3) fp32 -> MFMA A-fragment order, split hi/lo bf16.
// ---------------------------------------------------------------------------
__global__ __launch_bounds__(256) void pack_w(
    const float* __restrict__ W, short* __restrict__ whi, short* __restrict__ wlo,
    int ICBC) {
  int id = blockIdx.x * 256 + threadIdx.x;
  int total = 2 * 9 * ICBC * 64 * 8;
  if (id >= total) return;
  int r    = id & 7;
  int lane = (id >> 3) & 63;
  int rest = id >> 9;
  int icb  = rest % ICBC;
  int mtt  = rest / ICBC;
  int tap  = mtt % 9;
  int mt   = mtt / 9;
  int oc = mt * 32 + (lane & 31);
  int ic = icb * 16 + ((lane >> 5) << 3) + r;
  int ky = tap / 3, kx = tap % 3;
  int IC = ICBC * 16;
  float v = W[(((long)oc * IC + ic) * 3 + ky) * 3 + kx];
  unsigned short h = f2bf(v);
  unsigned short l = f2bf(v - bf2f(h));
  whi[id] = (short)h;
  wlo[id] = (short)l;
}

// ---------------------------------------------------------------------------
// conv_body: 3x3 SAME conv partial, implicit-GEMM split-bf16 MFMA 32x32x16.
// Each wave computes 2 OUTPUT ROWS -> one wh/wl load pair feeds 6 MFMAs
// (2 rows x {accA=wh*xh; accB=wl*xh; accB+=wh*xl}), halving weight traffic
// per output and giving 2 independent MFMA chains per load. Block = 4 waves:
// wave = (mt = wid&1, rp = wid>>1), covers rows by4..by4+3, 32 px, 64 oc.
// LDS stages 6 rows (4 out + 2 halo) x 36 slots x 16ic, hi+lo, NICB icbs
// via global_load_lds (linear chunk->LDS, per-lane global src, one barrier).
// Weights from fragment-ordered global (block-uniform, L2-resident, L1-hit).
// Concrete __global__ wrappers (r10 lesson: template __global__ stubs get
// dropped). z = n*KG + kg; kg reduces NICB icbs -> fp32 partial.
// ---------------------------------------------------------------------------
template <int ICBT, int KG>
__device__ __forceinline__ void conv_body(
    const short* __restrict__ xhi, const short* __restrict__ xlo,
    const short* __restrict__ whi, const short* __restrict__ wlo,
    float* __restrict__ part, short* __restrict__ sx) {
  constexpr int NICB  = ICBT / KG;
  constexpr int TOTCH = NICB * 864;               // 16B chunks: NICB*2hl*6rows*72
  const int tid  = threadIdx.x;
  const int lane = tid & 63;
  const int wid  = tid >> 6;
  const int mt   = wid & 1;
  const int rp   = wid >> 1;                      // row-pair 0..1
  const int g    = (lane >> 5) & 1;
  const int bx   = blockIdx.x * 32;
  const int by4  = blockIdx.y * 4;
  const int z    = blockIdx.z;
  const int kg   = z % KG;
  const int n    = z / KG;
  const int icb0 = kg * NICB;

  // Staging: chunk c -> LDS c*16B (linear); c = [ii][hl][row r 0..5][k 0..71];
  // global src = slab row base + k*16B.
#pragma unroll
  for (int i = 0; i < (TOTCH + 255) / 256; ++i) {
    int c = i * 256 + wid * 64 + lane;
    if (c < TOTCH) {
      int ii   = c / 864;
      int rem  = c - ii * 864;
      int hl   = rem / 432;
      int rem2 = rem - hl * 432;
      int r = rem2 / 72, k = rem2 - r * 72;
      const short* src = (hl ? xlo : xhi)
          + ((long)(n * ICBT + icb0 + ii) * PPX_ + (long)(by4 + r) * PROW_ + bx) * 16 + k * 8;
      __builtin_amdgcn_global_load_lds(src, &sx[c * 8], 16, 0, 0);
    }
  }
  __syncthreads();

  f32x16 accA0, accB0, accA1, accB1;
#pragma unroll
  for (int i = 0; i < 16; ++i) { accA0[i] = 0.f; accB0[i] = 0.f; accA1[i] = 0.f; accB1[i] = 0.f; }

#pragma unroll
  for (int ii = 0; ii < NICB; ++ii) {
#pragma unroll
    for (int tap = 0; tap < 9; ++tap) {
      const int dy = tap / 3, dx = tap % 3;
      // sx layout: ii*6912 + hl*3456 + row*576 + slot*16 + g*8
      const int sbase = ii * 6912 + (2 * rp + dy) * 576 + ((lane & 31) + dx) * 16 + g * 8;
      bf16x8 xh0 = *(const bf16x8*)&sx[sbase];
      bf16x8 xl0 = *(const bf16x8*)&sx[sbase + 3456];
      bf16x8 xh1 = *(const bf16x8*)&sx[sbase + 576];
      bf16x8 xl1 = *(const bf16x8*)&sx[sbase + 3456 + 576];
      long wi = ((long)((mt * 9 + tap) * ICBT + icb0 + ii)) * 512 + lane * 8;
      bf16x8 wh = *(const bf16x8*)(whi + wi);
      bf16x8 wl = *(const bf16x8*)(wlo + wi);
      accA0 = __builtin_amdgcn_mfma_f32_32x32x16_bf16(wh, xh0, accA0, 0, 0, 0);
      accA1 = __builtin_amdgcn_mfma_f32_32x32x16_bf16(wh, xh1, accA1, 0, 0, 0);
      accB0 = __builtin_amdgcn_mfma_f32_32x32x16_bf16(wl, xh0, accB0, 0, 0, 0);
      accB1 = __builtin_amdgcn_mfma_f32_32x32x16_bf16(wl, xh1, accB1, 0, 0, 0);
      accB0 = __builtin_amdgcn_mfma_f32_32x32x16_bf16(wh, xl0, accB0, 0, 0, 0);
      accB1 = __builtin_amdgcn_mfma_f32_32x32x16_bf16(wh, xl1, accB1, 0, 0, 0);
    }
  }

  int pxg = bx + (lane & 31);
  if (pxg < W_) {
    long base0 = (long)z * 64 * HW_ + (long)(by4 + 2 * rp) * W_ + pxg;
    long base1 = base0 + W_;
#pragma unroll
    for (int r = 0; r < 16; ++r) {
      int oc = mt * 32 + (r & 3) + 8 * (r >> 2) + 4 * g;
      part[base0 + (long)oc * HW_] = accA0[r] + accB0[r];
      part[base1 + (long)oc * HW_] = accA1[r] + accB1[r];
    }
  }
}

__global__ __launch_bounds__(256) void conv1_mfma(
    const short* __restrict__ xhi, const short* __restrict__ xlo,
    const short* __restrict__ whi, const short* __restrict__ wlo,
    float* __restrict__ part) {
  __shared__ alignas(16) short sx[2 * 6912];   // NICB=2 -> 27648 B
  conv_body<12, 6>(xhi, xlo, whi, wlo, part, sx);
}

__global__ __launch_bounds__(256) void conv2_mfma(
    const short* __restrict__ xhi, const short* __restrict__ xlo,
    const short* __restrict__ whi, const short* __restrict__ wlo,
    float* __restrict__ part) {
  __shared__ alignas(16) short sx[1 * 6912];   // NICB=1 -> 13824 B
  conv_body<4, 4>(xhi, xlo, whi, wlo, part, sx);
}

// ---------------------------------------------------------------------------
// combine1: h1 = lrelu(sum_kg part + bias) -> packed padded hi/lo (conv2 in).
// ---------------------------------------------------------------------------
template <int KG>
__global__ __launch_bounds__(256) void combine1(
    const float* __restrict__ part, const float* __restrict__ bias,
    short* __restrict__ ohi, short* __restrict__ olo) {
  __shared__ float sm[16][113];
  int bid = blockIdx.x;
  int y   = bid % H_;
  int icb = (bid / H_) % 4;
  int n   = bid / (H_ * 4);
  int tid = threadIdx.x;
  for (int i = tid; i < 16 * 112; i += 256) {
    int c = i / 112, x = i - c * 112;
    int oc = icb * 16 + c;
    long hw = (long)y * W_ + x;
    float v = bias[oc];
#pragma unroll
    for (int k = 0; k < KG; ++k)
      v += part[((long)(n * KG + k) * 64 + oc) * HW_ + hw];
    v = v > 0.f ? v : v * SLOPE_;
    sm[c][x] = v;
  }
  __syncthreads();
  if (tid < 224) {
    int px = tid >> 1, gg = tid & 1;
    unsigned hh[8], ll[8];
#pragma unroll
    for (int j = 0; j < 8; ++j) {
      float v = sm[gg * 8 + j][px];
      hh[j] = f2bf(v);
      ll[j] = f2bf(v - bf2f((unsigned short)hh[j]));
    }
    long o = ((long)(n * 4 + icb) * PPX_ + (long)(y + 1) * PROW_ + (px + 1)) * 16 + gg * 8;
    uint4 uh, ul;
    uh.x = hh[0] | (hh[1] << 16); uh.y = hh[2] | (hh[3] << 16);
    uh.z = hh[4] | (hh[5] << 16); uh.w = hh[6] | (hh[7] << 16);
    ul.x = ll[0] | (ll[1] << 16); ul.y = ll[2] | (ll[3] << 16);
    ul.z = ll[4] | (ll[5] << 16); ul.w = ll[6] | (ll[7] << 16);
    *(uint4*)(ohi + o) = uh;
    *(uint4*)(olo + o) = ul;
  }
}

// ---------------------------------------------------------------------------
// combine2: out[t] += sum_kg part + bias (residual already in out[t]).
// ---------------------------------------------------------------------------
template <int KG>
__global__ __launch_bounds__(256) void combine2(
    const float* __restrict__ part, const float* __restrict__ bias,
    float* __restrict__ out_t) {
  int id = blockIdx.x * 256 + threadIdx.x;
  if (id >= N_ * C_ * HW_) return;
  int hw = id % HW_;
  int oc = (id / HW_) % C_;
  int n  = id / (HW_ * C_);
  long o = (long)n * T_ * C_ * HW_ + (long)oc * HW_ + hw;
  float v = bias[oc] + out_t[o];
#pragma unroll
  for (int k = 0; k < KG; ++k)
    v += part[((long)(n * KG + k) * 64 + oc) * HW_ + hw];
  out_t[o] = v;
}

// ---------------------------------------------------------------------------
// Host-side orchestration
// ---------------------------------------------------------------------------
constexpr int KG1 = 6;   // conv1: NICB=2, grid 4x28x12=1344 blocks, part 38.5MB
constexpr int KG2 = 4;   // conv2: NICB=1, grid 4x28x8=896 blocks

struct Bufs {
  float* part;
  short *xhi, *xlo, *h1hi, *h1lo, *w1hi, *w1lo, *w2hi, *w2lo;
};

static void run_step(float* out, const float* flows, int t, bool fwd, int i,
                     const float* b1, const float* b2, const Bufs& B,
                     hipStream_t stream) {
  const float* curr = out + (long)t * C_ * HW_;
  const float* p1 = nullptr;
  const float* p2 = nullptr;
  const float* f1 = nullptr;
  const float* f2 = nullptr;
  if (fwd) {
    if (t >= 1) { p1 = out + (long)(t - 1) * C_ * HW_; f1 = flows + (long)(t - 1) * 2 * HW_; }
    if (t >= 2) { p2 = out + (long)(t - 2) * C_ * HW_; f2 = flows + (long)(t - 2) * 2 * HW_; }
  } else {
    if (i >= 1) { p1 = out + (long)(t + 1) * C_ * HW_; f1 = flows + (long)(t + 1) * 2 * HW_; }
    if (i >= 2) { p2 = out + (long)(t + 2) * C_ * HW_; f2 = flows + (long)(t + 2) * 2 * HW_; }
  }

  warp_pack<<<N_ * 12 * H_, 256, 0, stream>>>(curr, p1, p2, f1, f2, B.xhi, B.xlo);
  conv1_mfma<<<dim3(4, 28, N_ * KG1), 256, 0, stream>>>(
      B.xhi, B.xlo, B.w1hi, B.w1lo, B.part);
  combine1<KG1><<<N_ * 4 * H_, 256, 0, stream>>>(B.part, b1, B.h1hi, B.h1lo);
  conv2_mfma<<<dim3(4, 28, N_ * KG2), 256, 0, stream>>>(
      B.h1hi, B.h1lo, B.w2hi, B.w2lo, B.part);
  combine2<KG2><<<(N_ * C_ * HW_ + 255) / 256, 256, 0, stream>>>(
      B.part, b2, out + (long)t * C_ * HW_);
}

extern "C" void kernel_launch(void* const* d_in, const int* in_sizes, int n_in,
                              void* d_out, int out_size, void* d_ws, size_t ws_size,
                              hipStream_t stream) {
  const float* feats = (const float*)d_in[0];
  const float* fflow = (const float*)d_in[1];
  const float* bflow = (const float*)d_in[2];
  const float* W1 = (const float*)d_in[3];
  const float* b1 = (const float*)d_in[4];
  const float* W2 = (const float*)d_in[5];
  const float* b2 = (const float*)d_in[6];
  float* out = (float*)d_out;

  char* p = (char*)d_ws;
  auto carve = [&](size_t bytes) {
    void* r = (void*)p;
    p += (bytes + 255) & ~(size_t)255;
    return r;
  };
  Bufs B;
  size_t xpack_sh  = (size_t)N_ * 12 * PPX_ * 16;
  size_t h1pack_sh = (size_t)N_ * 4 * PPX_ * 16;
  B.part = (float*)carve(sizeof(float) * (size_t)KG1 * N_ * 64 * HW_);
  B.xhi  = (short*)carve(2 * xpack_sh);
  B.xlo  = (short*)carve(2 * xpack_sh);
  B.h1hi = (short*)carve(2 * h1pack_sh);
  B.h1lo = (short*)carve(2 * h1pack_sh);
  B.w1hi = (short*)carve(2 * (size_t)(2 * 9 * 12 * 64 * 8));
  B.w1lo = (short*)carve(2 * (size_t)(2 * 9 * 12 * 64 * 8));
  B.w2hi = (short*)carve(2 * (size_t)(2 * 9 * 4 * 64 * 8));
  B.w2lo = (short*)carve(2 * (size_t)(2 * 9 * 4 * 64 * 8));

  // Zero only the pad rings (interior fully rewritten every step).
  {
    constexpr int PXH = 2 * PROW_ + 112 * 19;
    int total = (24 + 8) * 2 * PXH;
    halo_zero<<<(total + 255) / 256, 256, 0, stream>>>(B.xhi, B.xlo, B.h1hi, B.h1lo);
  }

  // Weight fragments (hi/lo split), once per launch.
  pack_w<<<(2 * 9 * 12 * 64 * 8 + 255) / 256, 256, 0, stream>>>(W1, B.w1hi, B.w1lo, 12);
  pack_w<<<(2 * 9 * 4 * 64 * 8 + 255) / 256, 256, 0, stream>>>(W2, B.w2hi, B.w2lo, 4);

  // Seed the working feats (in d_out) with the input feats.
  hipMemcpyAsync(out, feats, sizeof(float) * (size_t)N_ * T_ * C_ * HW_,
                 hipMemcpyDeviceToDevice, stream);

  for (int t = 0; t < T_; ++t)
    run_step(out, fflow, t, true, t, b1, b2, B, stream);
  for (int i = 0; i < T_; ++i) {
    int t = T_ - 1 - i;
    run_step(out, bflow, t, false, i, b1, b2, B, stream);
  }
}

// Round 17
// 1846.555 us; speedup vs baseline: 1.1893x; 1.0231x over previous
//
#include <hip/hip_runtime.h>

// Problem constants (fixed by reference)
constexpr int N_ = 2, T_ = 12, C_ = 64, H_ = 112, W_ = 112;
constexpr int HW_ = H_ * W_;
constexpr float SLOPE_ = 0.1f;
// Padded packed h1 layout: rows -1..112 (114), cols -1..129 (131)
constexpr int PROW_ = 131;
constexpr int PNROW_ = 114;
constexpr int PPX_ = PROW_ * PNROW_;

typedef short bf16x8 __attribute__((ext_vector_type(8)));
typedef float f32x16 __attribute__((ext_vector_type(16)));

__device__ __forceinline__ unsigned short f2bf(float f) {
  unsigned u = __float_as_uint(f);
  unsigned r = (u + 0x7fffu + ((u >> 16) & 1u)) >> 16;
  return (unsigned short)r;
}
__device__ __forceinline__ float bf2f(unsigned short h) {
  return __uint_as_float(((unsigned)h) << 16);
}

// ---------------------------------------------------------------------------
// Bilinear helpers (zero padding outside, matches reference flow_warp).
// ---------------------------------------------------------------------------
__device__ __forceinline__ float samp_one(const float* __restrict__ img, int y, int x) {
  if ((unsigned)x < (unsigned)W_ && (unsigned)y < (unsigned)H_)
    return img[y * W_ + x];
  return 0.f;
}

__device__ __forceinline__ float bilin(const float* __restrict__ img, float vx, float vy) {
  float x0f = floorf(vx), y0f = floorf(vy);
  int x0 = (int)x0f, y0 = (int)y0f;
  float wx = vx - x0f, wy = vy - y0f;
  float g00 = samp_one(img, y0,     x0);
  float g01 = samp_one(img, y0,     x0 + 1);
  float g10 = samp_one(img, y0 + 1, x0);
  float g11 = samp_one(img, y0 + 1, x0 + 1);
  return g00 * (1.f - wx) * (1.f - wy)
       + g01 * wx * (1.f - wy)
       + g10 * (1.f - wx) * wy
       + g11 * wx * wy;
}

// 8-channel bilinear with hoisted weights/masks (corner validity per ref).
__device__ __forceinline__ void bilin8(const float* __restrict__ sp, float vx, float vy,
                                       float* __restrict__ v) {
  float x0f = floorf(vx), y0f = floorf(vy);
  int x0 = (int)x0f, y0 = (int)y0f;
  float wx = vx - x0f, wy = vy - y0f;
  float w00 = (1.f - wx) * (1.f - wy), w01 = wx * (1.f - wy);
  float w10 = (1.f - wx) * wy,         w11 = wx * wy;
  bool bx0 = (unsigned)x0 < (unsigned)W_, bx1 = (unsigned)(x0 + 1) < (unsigned)W_;
  bool by0 = (unsigned)y0 < (unsigned)H_, by1 = (unsigned)(y0 + 1) < (unsigned)H_;
  float mw00 = (bx0 && by0) ? w00 : 0.f;
  float mw01 = (bx1 && by0) ? w01 : 0.f;
  float mw10 = (bx0 && by1) ? w10 : 0.f;
  float mw11 = (bx1 && by1) ? w11 : 0.f;
  int cx0 = min(max(x0, 0), W_ - 1), cx1 = min(max(x0 + 1, 0), W_ - 1);
  int cy0 = min(max(y0, 0), H_ - 1), cy1 = min(max(y0 + 1, 0), H_ - 1);
  long o00 = (long)cy0 * W_ + cx0, o01 = (long)cy0 * W_ + cx1;
  long o10 = (long)cy1 * W_ + cx0, o11 = (long)cy1 * W_ + cx1;
#pragma unroll
  for (int j = 0; j < 8; ++j) {
    const float* pj = sp + (long)j * HW_;
    v[j] = pj[o00] * mw00 + pj[o01] * mw01 + pj[o10] * mw10 + pj[o11] * mw11;
  }
}

// ---------------------------------------------------------------------------
// halo_zero: zero the pad ring of the h1 packed buffers (8 slabs, hi+lo).
// ---------------------------------------------------------------------------
__global__ __launch_bounds__(256) void halo_zero(
    short* __restrict__ h1hi, short* __restrict__ h1lo) {
  constexpr int PXH = 2 * PROW_ + 112 * 19;   // 2390 halo pixels per slab
  int id = blockIdx.x * 256 + threadIdx.x;
  int total = 8 * 2 * PXH;
  if (id >= total) return;
  int p  = id % PXH;
  int sb = id / PXH;
  int row, col;
  if (p < 2 * PROW_) { row = (p < PROW_) ? 0 : PNROW_ - 1; col = p % PROW_; }
  else { int q = p - 2 * PROW_; row = 1 + q / 19; int c19 = q % 19; col = c19 ? 112 + c19 : 0; }
  short* base = (sb & 1) ? h1lo : h1hi;
  base += ((long)(sb >> 1)) * PPX_ * 16;
  short* q16 = base + ((long)row * PROW_ + col) * 16;
  *(uint4*)q16 = uint4{0, 0, 0, 0};
  *(uint4*)(q16 + 8) = uint4{0, 0, 0, 0};
}

// ---------------------------------------------------------------------------
// pack_w: W (64, IC, 3, 3) fp32 -> MFMA A-fragment order, split hi/lo bf16.
// ---------------------------------------------------------------------------
__global__ __launch_bounds__(256) void pack_w(
    const float* __restrict__ W, short* __restrict__ whi, short* __restrict__ wlo,
    int ICBC) {
  int id = blockIdx.x * 256 + threadIdx.x;
  int total = 2 * 9 * ICBC * 64 * 8;
  if (id >= total) return;
  int r    = id & 7;
  int lane = (id >> 3) & 63;
  int rest = id >> 9;
  int icb  = rest % ICBC;
  int mtt  = rest / ICBC;
  int tap  = mtt % 9;
  int mt   = mtt / 9;
  int oc = mt * 32 + (lane & 31);
  int ic = icb * 16 + ((lane >> 5) << 3) + r;
  int ky = tap / 3, kx = tap % 3;
  int IC = ICBC * 16;
  float v = W[(((long)oc * IC + ic) * 3 + ky) * 3 + kx];
  unsigned short h = f2bf(v);
  unsigned short l = f2bf(v - bf2f(h));
  whi[id] = (short)h;
  wlo[id] = (short)l;
}

// ---------------------------------------------------------------------------
// warp_conv1: FUSED warp+pack+conv1 partial (r16 post-mortem: warp_pack's
// 39MB round trip + dispatch was pure overhead; the packed-x buffer existed
// only to feed conv1's LDS). Phase 1: each block computes its own 6-row x
// 36-px aggr window (fp32 bilinear warp -> hi/lo split -> ds_write_b128)
// into the EXACT LDS layout the verified r16 MFMA loop reads. With KG=6 /
// NICB=2, both icbs of a block share one slot type (curr / warp-p1 /
// warp-p2) -> block-uniform branch; warp work partitions across kg (no
// duplication; only 6/4 x 36/32 halo redundancy). Adjacent lanes write
// adjacent 16B chunks -> conflict-free. Phase 2: unchanged 2-row-per-wave
// MFMA loop (wave = (mt, rp); one wh/wl pair feeds 6 MFMAs).
// z = n*KG + kg -> fp32 partial part[z][64 oc][HW].
// ---------------------------------------------------------------------------
__global__ __launch_bounds__(256) void warp_conv1(
    const float* __restrict__ curr,   // t-slice of out, n-stride T*C*HW
    const float* __restrict__ p1,     // may be null
    const float* __restrict__ p2,     // may be null
    const float* __restrict__ f1,     // t-slice, n-stride T*2*HW (may be null)
    const float* __restrict__ f2,     // t-slice, n-stride T*2*HW (may be null)
    const short* __restrict__ whi, const short* __restrict__ wlo,
    float* __restrict__ part) {
  constexpr int ICBT = 12, KG = 6, NICB = 2;
  __shared__ alignas(16) short sx[NICB * 6912];   // 27648 B, r16 layout
  const int tid  = threadIdx.x;
  const int lane = tid & 63;
  const int wid  = tid >> 6;
  const int mt   = wid & 1;
  const int rp   = wid >> 1;
  const int g    = (lane >> 5) & 1;
  const int bx   = blockIdx.x * 32;
  const int by4  = blockIdx.y * 4;
  const int z    = blockIdx.z;
  const int kg   = z % KG;
  const int n    = z / KG;
  const int icb0 = kg * NICB;
  const int stype = icb0 >> 2;      // 0:curr 1:warp(p1) 2:warp(p2) — block-uniform
  const long fn = (long)n * T_ * C_ * HW_;

  const float* src = nullptr;
  if (stype == 1 && p1) src = p1;
  if (stype == 2 && p2) src = p2;
  const float* f1n = f1 ? f1 + (long)n * T_ * 2 * HW_ : nullptr;
  const float* f2n = f2 ? f2 + (long)n * T_ * 2 * HW_ : nullptr;

  // --- Phase 1: compute aggr window -> split -> LDS ---
  // sample s = [ii][r 0..5][k 0..71], k = slot*2+gg; image coords
  // gy = by4 + r - 1, gx = bx + slot - 1; 8 channels (icb&3)*16 + gg*8.
#pragma unroll
  for (int it = 0; it < 4; ++it) {            // ceil(864/256)
    int s = it * 256 + tid;
    if (s < NICB * 432) {
      int ii  = s / 432;
      int rem = s - ii * 432;
      int r   = rem / 72;
      int k   = rem - r * 72;
      int slot = k >> 1, gg = k & 1;
      int gy = by4 + r - 1;
      int gx = bx + slot - 1;
      int icb = icb0 + ii;
      int cbase = (icb & 3) * 16 + gg * 8;
      float v[8];
      bool inimg = ((unsigned)gy < (unsigned)H_) && ((unsigned)gx < (unsigned)W_);
      if (!inimg) {
#pragma unroll
        for (int j = 0; j < 8; ++j) v[j] = 0.f;
      } else if (src == nullptr) {
        const float* cp = curr + fn + (long)cbase * HW_ + (long)gy * W_ + gx;
#pragma unroll
        for (int j = 0; j < 8; ++j) v[j] = cp[(long)j * HW_];
      } else {
        long hw = (long)gy * W_ + gx;
        float vx, vy;
        if (stype == 1) {
          vx = (float)gx + f1n[hw];
          vy = (float)gy + f1n[HW_ + hw];
        } else {
          float ax = (float)gx + f1n[hw];
          float ay = (float)gy + f1n[HW_ + hw];
          vx = ax + bilin(f2n,       ax, ay);   // x + f2_tot.x
          vy = ay + bilin(f2n + HW_, ax, ay);   // y + f2_tot.y
        }
        bilin8(src + fn + (long)cbase * HW_, vx, vy, v);
      }
      unsigned hh[8], ll[8];
#pragma unroll
      for (int j = 0; j < 8; ++j) {
        hh[j] = f2bf(v[j]);
        ll[j] = f2bf(v[j] - bf2f((unsigned short)hh[j]));
      }
      uint4 uh{hh[0] | (hh[1] << 16), hh[2] | (hh[3] << 16),
               hh[4] | (hh[5] << 16), hh[6] | (hh[7] << 16)};
      uint4 ul{ll[0] | (ll[1] << 16), ll[2] | (ll[3] << 16),
               ll[4] | (ll[5] << 16), ll[6] | (ll[7] << 16)};
      short* b = sx + ii * 6912 + r * 576 + slot * 16 + gg * 8;
      *(uint4*)b = uh;
      *(uint4*)(b + 3456) = ul;
    }
  }
  __syncthreads();

  // --- Phase 2: unchanged r16 MFMA loop (2 output rows per wave) ---
  f32x16 accA0, accB0, accA1, accB1;
#pragma unroll
  for (int i = 0; i < 16; ++i) { accA0[i] = 0.f; accB0[i] = 0.f; accA1[i] = 0.f; accB1[i] = 0.f; }

#pragma unroll
  for (int ii = 0; ii < NICB; ++ii) {
#pragma unroll
    for (int tap = 0; tap < 9; ++tap) {
      const int dy = tap / 3, dx = tap % 3;
      const int sbase = ii * 6912 + (2 * rp + dy) * 576 + ((lane & 31) + dx) * 16 + g * 8;
      bf16x8 xh0 = *(const bf16x8*)&sx[sbase];
      bf16x8 xl0 = *(const bf16x8*)&sx[sbase + 3456];
      bf16x8 xh1 = *(const bf16x8*)&sx[sbase + 576];
      bf16x8 xl1 = *(const bf16x8*)&sx[sbase + 3456 + 576];
      long wi = ((long)((mt * 9 + tap) * ICBT + icb0 + ii)) * 512 + lane * 8;
      bf16x8 wh = *(const bf16x8*)(whi + wi);
      bf16x8 wl = *(const bf16x8*)(wlo + wi);
      accA0 = __builtin_amdgcn_mfma_f32_32x32x16_bf16(wh, xh0, accA0, 0, 0, 0);
      accA1 = __builtin_amdgcn_mfma_f32_32x32x16_bf16(wh, xh1, accA1, 0, 0, 0);
      accB0 = __builtin_amdgcn_mfma_f32_32x32x16_bf16(wl, xh0, accB0, 0, 0, 0);
      accB1 = __builtin_amdgcn_mfma_f32_32x32x16_bf16(wl, xh1, accB1, 0, 0, 0);
      accB0 = __builtin_amdgcn_mfma_f32_32x32x16_bf16(wh, xl0, accB0, 0, 0, 0);
      accB1 = __builtin_amdgcn_mfma_f32_32x32x16_bf16(wh, xl1, accB1, 0, 0, 0);
    }
  }

  int pxg = bx + (lane & 31);
  if (pxg < W_) {
    long base0 = (long)z * 64 * HW_ + (long)(by4 + 2 * rp) * W_ + pxg;
    long base1 = base0 + W_;
#pragma unroll
    for (int r = 0; r < 16; ++r) {
      int oc = mt * 32 + (r & 3) + 8 * (r >> 2) + 4 * g;
      part[base0 + (long)oc * HW_] = accA0[r] + accB0[r];
      part[base1 + (long)oc * HW_] = accA1[r] + accB1[r];
    }
  }
}

// ---------------------------------------------------------------------------
// conv_body (conv2 only): unchanged r16 structure — global_load_lds staging
// of packed h1, 2-row waves, weights global->L1. Concrete wrapper below.
// ---------------------------------------------------------------------------
template <int ICBT, int KG>
__device__ __forceinline__ void conv_body(
    const short* __restrict__ xhi, const short* __restrict__ xlo,
    const short* __restrict__ whi, const short* __restrict__ wlo,
    float* __restrict__ part, short* __restrict__ sx) {
  constexpr int NICB  = ICBT / KG;
  constexpr int TOTCH = NICB * 864;
  const int tid  = threadIdx.x;
  const int lane = tid & 63;
  const int wid  = tid >> 6;
  const int mt   = wid & 1;
  const int rp   = wid >> 1;
  const int g    = (lane >> 5) & 1;
  const int bx   = blockIdx.x * 32;
  const int by4  = blockIdx.y * 4;
  const int z    = blockIdx.z;
  const int kg   = z % KG;
  const int n    = z / KG;
  const int icb0 = kg * NICB;

#pragma unroll
  for (int i = 0; i < (TOTCH + 255) / 256; ++i) {
    int c = i * 256 + wid * 64 + lane;
    if (c < TOTCH) {
      int ii   = c / 864;
      int rem  = c - ii * 864;
      int hl   = rem / 432;
      int rem2 = rem - hl * 432;
      int r = rem2 / 72, k = rem2 - r * 72;
      const short* src = (hl ? xlo : xhi)
          + ((long)(n * ICBT + icb0 + ii) * PPX_ + (long)(by4 + r) * PROW_ + bx) * 16 + k * 8;
      __builtin_amdgcn_global_load_lds(src, &sx[c * 8], 16, 0, 0);
    }
  }
  __syncthreads();

  f32x16 accA0, accB0, accA1, accB1;
#pragma unroll
  for (int i = 0; i < 16; ++i) { accA0[i] = 0.f; accB0[i] = 0.f; accA1[i] = 0.f; accB1[i] = 0.f; }

#pragma unroll
  for (int ii = 0; ii < NICB; ++ii) {
#pragma unroll
    for (int tap = 0; tap < 9; ++tap) {
      const int dy = tap / 3, dx = tap % 3;
      const int sbase = ii * 6912 + (2 * rp + dy) * 576 + ((lane & 31) + dx) * 16 + g * 8;
      bf16x8 xh0 = *(const bf16x8*)&sx[sbase];
      bf16x8 xl0 = *(const bf16x8*)&sx[sbase + 3456];
      bf16x8 xh1 = *(const bf16x8*)&sx[sbase + 576];
      bf16x8 xl1 = *(const bf16x8*)&sx[sbase + 3456 + 576];
      long wi = ((long)((mt * 9 + tap) * ICBT + icb0 + ii)) * 512 + lane * 8;
      bf16x8 wh = *(const bf16x8*)(whi + wi);
      bf16x8 wl = *(const bf16x8*)(wlo + wi);
      accA0 = __builtin_amdgcn_mfma_f32_32x32x16_bf16(wh, xh0, accA0, 0, 0, 0);
      accA1 = __builtin_amdgcn_mfma_f32_32x32x16_bf16(wh, xh1, accA1, 0, 0, 0);
      accB0 = __builtin_amdgcn_mfma_f32_32x32x16_bf16(wl, xh0, accB0, 0, 0, 0);
      accB1 = __builtin_amdgcn_mfma_f32_32x32x16_bf16(wl, xh1, accB1, 0, 0, 0);
      accB0 = __builtin_amdgcn_mfma_f32_32x32x16_bf16(wh, xl0, accB0, 0, 0, 0);
      accB1 = __builtin_amdgcn_mfma_f32_32x32x16_bf16(wh, xl1, accB1, 0, 0, 0);
    }
  }

  int pxg = bx + (lane & 31);
  if (pxg < W_) {
    long base0 = (long)z * 64 * HW_ + (long)(by4 + 2 * rp) * W_ + pxg;
    long base1 = base0 + W_;
#pragma unroll
    for (int r = 0; r < 16; ++r) {
      int oc = mt * 32 + (r & 3) + 8 * (r >> 2) + 4 * g;
      part[base0 + (long)oc * HW_] = accA0[r] + accB0[r];
      part[base1 + (long)oc * HW_] = accA1[r] + accB1[r];
    }
  }
}

__global__ __launch_bounds__(256) void conv2_mfma(
    const short* __restrict__ xhi, const short* __restrict__ xlo,
    const short* __restrict__ whi, const short* __restrict__ wlo,
    float* __restrict__ part) {
  __shared__ alignas(16) short sx[1 * 6912];   // NICB=1 -> 13824 B
  conv_body<4, 4>(xhi, xlo, whi, wlo, part, sx);
}

// ---------------------------------------------------------------------------
// combine1: h1 = lrelu(sum_kg part + bias) -> packed padded hi/lo (conv2 in).
// ---------------------------------------------------------------------------
template <int KG>
__global__ __launch_bounds__(256) void combine1(
    const float* __restrict__ part, const float* __restrict__ bias,
    short* __restrict__ ohi, short* __restrict__ olo) {
  __shared__ float sm[16][113];
  int bid = blockIdx.x;
  int y   = bid % H_;
  int icb = (bid / H_) % 4;
  int n   = bid / (H_ * 4);
  int tid = threadIdx.x;
  for (int i = tid; i < 16 * 112; i += 256) {
    int c = i / 112, x = i - c * 112;
    int oc = icb * 16 + c;
    long hw = (long)y * W_ + x;
    float v = bias[oc];
#pragma unroll
    for (int k = 0; k < KG; ++k)
      v += part[((long)(n * KG + k) * 64 + oc) * HW_ + hw];
    v = v > 0.f ? v : v * SLOPE_;
    sm[c][x] = v;
  }
  __syncthreads();
  if (tid < 224) {
    int px = tid >> 1, gg = tid & 1;
    unsigned hh[8], ll[8];
#pragma unroll
    for (int j = 0; j < 8; ++j) {
      float v = sm[gg * 8 + j][px];
      hh[j] = f2bf(v);
      ll[j] = f2bf(v - bf2f((unsigned short)hh[j]));
    }
    long o = ((long)(n * 4 + icb) * PPX_ + (long)(y + 1) * PROW_ + (px + 1)) * 16 + gg * 8;
    uint4 uh, ul;
    uh.x = hh[0] | (hh[1] << 16); uh.y = hh[2] | (hh[3] << 16);
    uh.z = hh[4] | (hh[5] << 16); uh.w = hh[6] | (hh[7] << 16);
    ul.x = ll[0] | (ll[1] << 16); ul.y = ll[2] | (ll[3] << 16);
    ul.z = ll[4] | (ll[5] << 16); ul.w = ll[6] | (ll[7] << 16);
    *(uint4*)(ohi + o) = uh;
    *(uint4*)(olo + o) = ul;
  }
}

// ---------------------------------------------------------------------------
// combine2: out[t] += sum_kg part + bias (residual already in out[t]).
// ---------------------------------------------------------------------------
template <int KG>
__global__ __launch_bounds__(256) void combine2(
    const float* __restrict__ part, const float* __restrict__ bias,
    float* __restrict__ out_t) {
  int id = blockIdx.x * 256 + threadIdx.x;
  if (id >= N_ * C_ * HW_) return;
  int hw = id % HW_;
  int oc = (id / HW_) % C_;
  int n  = id / (HW_ * C_);
  long o = (long)n * T_ * C_ * HW_ + (long)oc * HW_ + hw;
  float v = bias[oc] + out_t[o];
#pragma unroll
  for (int k = 0; k < KG; ++k)
    v += part[((long)(n * KG + k) * 64 + oc) * HW_ + hw];
  out_t[o] = v;
}

// ---------------------------------------------------------------------------
// Host-side orchestration
// ---------------------------------------------------------------------------
constexpr int KG1 = 6;   // conv1: NICB=2, grid 4x28x12=1344 blocks
constexpr int KG2 = 4;   // conv2: NICB=1, grid 4x28x8=896 blocks

struct Bufs {
  float* part;
  short *h1hi, *h1lo, *w1hi, *w1lo, *w2hi, *w2lo;
};

static void run_step(float* out, const float* flows, int t, bool fwd, int i,
                     const float* b1, const float* b2, const Bufs& B,
                     hipStream_t stream) {
  const float* curr = out + (long)t * C_ * HW_;
  const float* p1 = nullptr;
  const float* p2 = nullptr;
  const float* f1 = nullptr;
  const float* f2 = nullptr;
  if (fwd) {
    if (t >= 1) { p1 = out + (long)(t - 1) * C_ * HW_; f1 = flows + (long)(t - 1) * 2 * HW_; }
    if (t >= 2) { p2 = out + (long)(t - 2) * C_ * HW_; f2 = flows + (long)(t - 2) * 2 * HW_; }
  } else {
    if (i >= 1) { p1 = out + (long)(t + 1) * C_ * HW_; f1 = flows + (long)(t + 1) * 2 * HW_; }
    if (i >= 2) { p2 = out + (long)(t + 2) * C_ * HW_; f2 = flows + (long)(t + 2) * 2 * HW_; }
  }

  warp_conv1<<<dim3(4, 28, N_ * KG1), 256, 0, stream>>>(
      curr, p1, p2, f1, f2, B.w1hi, B.w1lo, B.part);
  combine1<KG1><<<N_ * 4 * H_, 256, 0, stream>>>(B.part, b1, B.h1hi, B.h1lo);
  conv2_mfma<<<dim3(4, 28, N_ * KG2), 256, 0, stream>>>(
      B.h1hi, B.h1lo, B.w2hi, B.w2lo, B.part);
  combine2<KG2><<<(N_ * C_ * HW_ + 255) / 256, 256, 0, stream>>>(
      B.part, b2, out + (long)t * C_ * HW_);
}

extern "C" void kernel_launch(void* const* d_in, const int* in_sizes, int n_in,
                              void* d_out, int out_size, void* d_ws, size_t ws_size,
                              hipStream_t stream) {
  const float* feats = (const float*)d_in[0];
  const float* fflow = (const float*)d_in[1];
  const float* bflow = (const float*)d_in[2];
  const float* W1 = (const float*)d_in[3];
  const float* b1 = (const float*)d_in[4];
  const float* W2 = (const float*)d_in[5];
  const float* b2 = (const float*)d_in[6];
  float* out = (float*)d_out;

  char* p = (char*)d_ws;
  auto carve = [&](size_t bytes) {
    void* r = (void*)p;
    p += (bytes + 255) & ~(size_t)255;
    return r;
  };
  Bufs B;
  size_t h1pack_sh = (size_t)N_ * 4 * PPX_ * 16;
  B.part = (float*)carve(sizeof(float) * (size_t)KG1 * N_ * 64 * HW_);
  B.h1hi = (short*)carve(2 * h1pack_sh);
  B.h1lo = (short*)carve(2 * h1pack_sh);
  B.w1hi = (short*)carve(2 * (size_t)(2 * 9 * 12 * 64 * 8));
  B.w1lo = (short*)carve(2 * (size_t)(2 * 9 * 12 * 64 * 8));
  B.w2hi = (short*)carve(2 * (size_t)(2 * 9 * 4 * 64 * 8));
  B.w2lo = (short*)carve(2 * (size_t)(2 * 9 * 4 * 64 * 8));

  // Zero only the h1 pad rings (interior fully rewritten every step).
  {
    constexpr int PXH = 2 * PROW_ + 112 * 19;
    int total = 8 * 2 * PXH;
    halo_zero<<<(total + 255) / 256, 256, 0, stream>>>(B.h1hi, B.h1lo);
  }

  // Weight fragments (hi/lo split), once per launch.
  pack_w<<<(2 * 9 * 12 * 64 * 8 + 255) / 256, 256, 0, stream>>>(W1, B.w1hi, B.w1lo, 12);
  pack_w<<<(2 * 9 * 4 * 64 * 8 + 255) / 256, 256, 0, stream>>>(W2, B.w2hi, B.w2lo, 4);

  // Seed the working feats (in d_out) with the input feats.
  hipMemcpyAsync(out, feats, sizeof(float) * (size_t)N_ * T_ * C_ * HW_,
                 hipMemcpyDeviceToDevice, stream);

  for (int t = 0; t < T_; ++t)
    run_step(out, fflow, t, true, t, b1, b2, B, stream);
  for (int i = 0; i < T_; ++i) {
    int t = T_ - 1 - i;
    run_step(out, bflow, t, false, i, b1, b2, B, stream);
  }
}

// Round 18
// 1630.919 us; speedup vs baseline: 1.3465x; 1.1322x over previous
//
#include <hip/hip_runtime.h>

// Problem constants (fixed by reference)
constexpr int N_ = 2, T_ = 12, C_ = 64, H_ = 112, W_ = 112;
constexpr int HW_ = H_ * W_;
constexpr float SLOPE_ = 0.1f;
// Padded packed h1 layout: rows -1..112 (114), cols -1..129 (131)
constexpr int PROW_ = 131;
constexpr int PNROW_ = 114;
constexpr int PPX_ = PROW_ * PNROW_;
// Packed fp32 working-feats layout: [n][t][cg 0..3][HW][16ch]
constexpr int PHW_ = HW_ * 16;            // floats per (n,t,cg) plane
constexpr long NSTW_ = (long)T_ * 4 * PHW_;  // n-stride in floats

typedef short bf16x8 __attribute__((ext_vector_type(8)));
typedef float f32x16 __attribute__((ext_vector_type(16)));

__device__ __forceinline__ unsigned short f2bf(float f) {
  unsigned u = __float_as_uint(f);
  unsigned r = (u + 0x7fffu + ((u >> 16) & 1u)) >> 16;
  return (unsigned short)r;
}
__device__ __forceinline__ float bf2f(unsigned short h) {
  return __uint_as_float(((unsigned)h) << 16);
}

// ---------------------------------------------------------------------------
// Scalar bilinear (for the 2-channel flow in f2_tot), zero-pad outside.
// ---------------------------------------------------------------------------
__device__ __forceinline__ float samp_one(const float* __restrict__ img, int y, int x) {
  if ((unsigned)x < (unsigned)W_ && (unsigned)y < (unsigned)H_)
    return img[y * W_ + x];
  return 0.f;
}

__device__ __forceinline__ float bilin(const float* __restrict__ img, float vx, float vy) {
  float x0f = floorf(vx), y0f = floorf(vy);
  int x0 = (int)x0f, y0 = (int)y0f;
  float wx = vx - x0f, wy = vy - y0f;
  float g00 = samp_one(img, y0,     x0);
  float g01 = samp_one(img, y0,     x0 + 1);
  float g10 = samp_one(img, y0 + 1, x0);
  float g11 = samp_one(img, y0 + 1, x0 + 1);
  return g00 * (1.f - wx) * (1.f - wy)
       + g01 * wx * (1.f - wy)
       + g10 * (1.f - wx) * wy
       + g11 * wx * wy;
}

// 8-channel bilinear from the PACKED layout: corner = 2 coalesced float4
// loads (32B contiguous). sp = base of [HW][16] plane; gg selects 8-ch half.
__device__ __forceinline__ void bilin8p(const float* __restrict__ sp, int gg,
                                        float vx, float vy, float* __restrict__ v) {
  float x0f = floorf(vx), y0f = floorf(vy);
  int x0 = (int)x0f, y0 = (int)y0f;
  float wx = vx - x0f, wy = vy - y0f;
  float w00 = (1.f - wx) * (1.f - wy), w01 = wx * (1.f - wy);
  float w10 = (1.f - wx) * wy,         w11 = wx * wy;
  bool bx0 = (unsigned)x0 < (unsigned)W_, bx1 = (unsigned)(x0 + 1) < (unsigned)W_;
  bool by0 = (unsigned)y0 < (unsigned)H_, by1 = (unsigned)(y0 + 1) < (unsigned)H_;
  float m00 = (bx0 && by0) ? w00 : 0.f;
  float m01 = (bx1 && by0) ? w01 : 0.f;
  float m10 = (bx0 && by1) ? w10 : 0.f;
  float m11 = (bx1 && by1) ? w11 : 0.f;
  int cx0 = min(max(x0, 0), W_ - 1), cx1 = min(max(x0 + 1, 0), W_ - 1);
  int cy0 = min(max(y0, 0), H_ - 1), cy1 = min(max(y0 + 1, 0), H_ - 1);
  const float* q00 = sp + ((long)cy0 * W_ + cx0) * 16 + gg * 8;
  const float* q01 = sp + ((long)cy0 * W_ + cx1) * 16 + gg * 8;
  const float* q10 = sp + ((long)cy1 * W_ + cx0) * 16 + gg * 8;
  const float* q11 = sp + ((long)cy1 * W_ + cx1) * 16 + gg * 8;
  float4 a00 = *(const float4*)q00, b00 = *(const float4*)(q00 + 4);
  float4 a01 = *(const float4*)q01, b01 = *(const float4*)(q01 + 4);
  float4 a10 = *(const float4*)q10, b10 = *(const float4*)(q10 + 4);
  float4 a11 = *(const float4*)q11, b11 = *(const float4*)(q11 + 4);
  const float* p00 = (const float*)&a00;
  const float* p01 = (const float*)&a01;
  const float* p10 = (const float*)&a10;
  const float* p11 = (const float*)&a11;
#pragma unroll
  for (int j = 0; j < 4; ++j)
    v[j] = p00[j] * m00 + p01[j] * m01 + p10[j] * m10 + p11[j] * m11;
  p00 = (const float*)&b00; p01 = (const float*)&b01;
  p10 = (const float*)&b10; p11 = (const float*)&b11;
#pragma unroll
  for (int j = 0; j < 4; ++j)
    v[4 + j] = p00[j] * m00 + p01[j] * m01 + p10[j] * m10 + p11[j] * m11;
}

// ---------------------------------------------------------------------------
// pack_feats: NCHW fp32 feats -> packed working buffer Wf [n][t][cg][HW][16].
// Block = (nt, cg, y); LDS transpose, coalesced both sides. Once per launch.
// ---------------------------------------------------------------------------
__global__ __launch_bounds__(256) void pack_feats(
    const float* __restrict__ feats, float* __restrict__ Wf) {
  __shared__ float sm[16][113];
  int bid = blockIdx.x;
  int y   = bid % H_;
  int cg  = (bid / H_) % 4;
  int nt  = bid / (H_ * 4);
  int tid = threadIdx.x;
  const float* src = feats + ((long)nt * C_ + cg * 16) * HW_ + (long)y * W_;
  for (int i = tid; i < 16 * 112; i += 256) {
    int c = i / 112, x = i - c * 112;
    sm[c][x] = src[(long)c * HW_ + x];
  }
  __syncthreads();
  if (tid < 224) {
    int px = tid >> 1, gg = tid & 1;
    float* dst = Wf + ((long)nt * 4 + cg) * PHW_ + ((long)y * W_ + px) * 16 + gg * 8;
    float4 a{sm[gg * 8 + 0][px], sm[gg * 8 + 1][px], sm[gg * 8 + 2][px], sm[gg * 8 + 3][px]};
    float4 b{sm[gg * 8 + 4][px], sm[gg * 8 + 5][px], sm[gg * 8 + 6][px], sm[gg * 8 + 7][px]};
    *(float4*)dst = a;
    *(float4*)(dst + 4) = b;
  }
}

// ---------------------------------------------------------------------------
// halo_zero: zero the pad ring of the h1 packed buffers (8 slabs, hi+lo).
// ---------------------------------------------------------------------------
__global__ __launch_bounds__(256) void halo_zero(
    short* __restrict__ h1hi, short* __restrict__ h1lo) {
  constexpr int PXH = 2 * PROW_ + 112 * 19;
  int id = blockIdx.x * 256 + threadIdx.x;
  int total = 8 * 2 * PXH;
  if (id >= total) return;
  int p  = id % PXH;
  int sb = id / PXH;
  int row, col;
  if (p < 2 * PROW_) { row = (p < PROW_) ? 0 : PNROW_ - 1; col = p % PROW_; }
  else { int q = p - 2 * PROW_; row = 1 + q / 19; int c19 = q % 19; col = c19 ? 112 + c19 : 0; }
  short* base = (sb & 1) ? h1lo : h1hi;
  base += ((long)(sb >> 1)) * PPX_ * 16;
  short* q16 = base + ((long)row * PROW_ + col) * 16;
  *(uint4*)q16 = uint4{0, 0, 0, 0};
  *(uint4*)(q16 + 8) = uint4{0, 0, 0, 0};
}

// ---------------------------------------------------------------------------
// pack_w: W (64, IC, 3, 3) fp32 -> MFMA A-fragment order, split hi/lo bf16.
// ---------------------------------------------------------------------------
__global__ __launch_bounds__(256) void pack_w(
    const float* __restrict__ W, short* __restrict__ whi, short* __restrict__ wlo,
    int ICBC) {
  int id = blockIdx.x * 256 + threadIdx.x;
  int total = 2 * 9 * ICBC * 64 * 8;
  if (id >= total) return;
  int r    = id & 7;
  int lane = (id >> 3) & 63;
  int rest = id >> 9;
  int icb  = rest % ICBC;
  int mtt  = rest / ICBC;
  int tap  = mtt % 9;
  int mt   = mtt / 9;
  int oc = mt * 32 + (lane & 31);
  int ic = icb * 16 + ((lane >> 5) << 3) + r;
  int ky = tap / 3, kx = tap % 3;
  int IC = ICBC * 16;
  float v = W[(((long)oc * IC + ic) * 3 + ky) * 3 + kx];
  unsigned short h = f2bf(v);
  unsigned short l = f2bf(v - bf2f(h));
  whi[id] = (short)h;
  wlo[id] = (short)l;
}

// ---------------------------------------------------------------------------
// warp_conv1: fused warp+pack+conv1 partial, PACKED fp32 source (r17 fix:
// NCHW 4B gathers -> 2x float4 per corner, 4x fewer loads, coalesced).
// stype balancing: block kg handles icbs {kg, kg+6} (one cheap + one
// expensive slot type; r17 had 2x warp-p2 blocks -> 3:1 imbalance tail).
// Phase 2: unchanged r16 MFMA loop (2 output rows/wave, weight pair feeds
// 6 MFMAs); weight index uses the PERMUTED icb. z = n*KG+kg -> partial.
// ---------------------------------------------------------------------------
__global__ __launch_bounds__(256) void warp_conv1(
    const float* __restrict__ currP,  // packed t-slice, n-stride NSTW_
    const float* __restrict__ p1P,    // may be null
    const float* __restrict__ p2P,    // may be null
    const float* __restrict__ f1,     // NCHW t-slice, n-stride T*2*HW (may be null)
    const float* __restrict__ f2,     // NCHW t-slice (may be null)
    const short* __restrict__ whi, const short* __restrict__ wlo,
    float* __restrict__ part) {
  constexpr int ICBT = 12, KG = 6, NICB = 2;
  __shared__ alignas(16) short sx[NICB * 6912];   // r16 layout
  const int tid  = threadIdx.x;
  const int lane = tid & 63;
  const int wid  = tid >> 6;
  const int mt   = wid & 1;
  const int rp   = wid >> 1;
  const int g    = (lane >> 5) & 1;
  const int bx   = blockIdx.x * 32;
  const int by4  = blockIdx.y * 4;
  const int z    = blockIdx.z;
  const int kg   = z % KG;
  const int n    = z / KG;
  const long fnp = (long)n * NSTW_;

  const float* srcs[3] = { currP, p1P ? p1P : currP, p2P ? p2P : currP };
  const bool wf[3] = { false, p1P != nullptr, p2P != nullptr };
  const float* f1n = f1 ? f1 + (long)n * T_ * 2 * HW_ : nullptr;
  const float* f2n = f2 ? f2 + (long)n * T_ * 2 * HW_ : nullptr;

  // --- Phase 1: warp into LDS (sample s = [ii][r 0..5][k 0..71]) ---
#pragma unroll
  for (int it = 0; it < 4; ++it) {
    int s = it * 256 + tid;
    if (s < NICB * 432) {
      int ii  = s / 432;
      int rem = s - ii * 432;
      int r   = rem / 72;
      int k   = rem - r * 72;
      int slot = k >> 1, gg = k & 1;
      int gy = by4 + r - 1;
      int gx = bx + slot - 1;
      int icb = kg + 6 * ii;            // permuted: {kg, kg+6}
      int stype = icb >> 2;
      int cg  = icb & 3;
      const float* sp = srcs[stype] + fnp + (long)cg * PHW_;
      float v[8];
      bool inimg = ((unsigned)gy < (unsigned)H_) && ((unsigned)gx < (unsigned)W_);
      if (!inimg) {
#pragma unroll
        for (int j = 0; j < 8; ++j) v[j] = 0.f;
      } else if (!wf[stype]) {
        const float* q = sp + ((long)gy * W_ + gx) * 16 + gg * 8;
        float4 a = *(const float4*)q, b = *(const float4*)(q + 4);
        v[0] = a.x; v[1] = a.y; v[2] = a.z; v[3] = a.w;
        v[4] = b.x; v[5] = b.y; v[6] = b.z; v[7] = b.w;
      } else {
        long hw = (long)gy * W_ + gx;
        float vx, vy;
        if (stype == 1) {
          vx = (float)gx + f1n[hw];
          vy = (float)gy + f1n[HW_ + hw];
        } else {
          float ax = (float)gx + f1n[hw];
          float ay = (float)gy + f1n[HW_ + hw];
          vx = ax + bilin(f2n,       ax, ay);
          vy = ay + bilin(f2n + HW_, ax, ay);
        }
        bilin8p(sp, gg, vx, vy, v);
      }
      unsigned hh[8], ll[8];
#pragma unroll
      for (int j = 0; j < 8; ++j) {
        hh[j] = f2bf(v[j]);
        ll[j] = f2bf(v[j] - bf2f((unsigned short)hh[j]));
      }
      uint4 uh{hh[0] | (hh[1] << 16), hh[2] | (hh[3] << 16),
               hh[4] | (hh[5] << 16), hh[6] | (hh[7] << 16)};
      uint4 ul{ll[0] | (ll[1] << 16), ll[2] | (ll[3] << 16),
               ll[4] | (ll[5] << 16), ll[6] | (ll[7] << 16)};
      short* b = sx + ii * 6912 + r * 576 + slot * 16 + gg * 8;
      *(uint4*)b = uh;
      *(uint4*)(b + 3456) = ul;
    }
  }
  __syncthreads();

  // --- Phase 2: r16 MFMA loop, permuted weight icb ---
  f32x16 accA0, accB0, accA1, accB1;
#pragma unroll
  for (int i = 0; i < 16; ++i) { accA0[i] = 0.f; accB0[i] = 0.f; accA1[i] = 0.f; accB1[i] = 0.f; }

#pragma unroll
  for (int ii = 0; ii < NICB; ++ii) {
    const int icb = kg + 6 * ii;
#pragma unroll
    for (int tap = 0; tap < 9; ++tap) {
      const int dy = tap / 3, dx = tap % 3;
      const int sbase = ii * 6912 + (2 * rp + dy) * 576 + ((lane & 31) + dx) * 16 + g * 8;
      bf16x8 xh0 = *(const bf16x8*)&sx[sbase];
      bf16x8 xl0 = *(const bf16x8*)&sx[sbase + 3456];
      bf16x8 xh1 = *(const bf16x8*)&sx[sbase + 576];
      bf16x8 xl1 = *(const bf16x8*)&sx[sbase + 3456 + 576];
      long wi = ((long)((mt * 9 + tap) * ICBT + icb)) * 512 + lane * 8;
      bf16x8 wh = *(const bf16x8*)(whi + wi);
      bf16x8 wl = *(const bf16x8*)(wlo + wi);
      accA0 = __builtin_amdgcn_mfma_f32_32x32x16_bf16(wh, xh0, accA0, 0, 0, 0);
      accA1 = __builtin_amdgcn_mfma_f32_32x32x16_bf16(wh, xh1, accA1, 0, 0, 0);
      accB0 = __builtin_amdgcn_mfma_f32_32x32x16_bf16(wl, xh0, accB0, 0, 0, 0);
      accB1 = __builtin_amdgcn_mfma_f32_32x32x16_bf16(wl, xh1, accB1, 0, 0, 0);
      accB0 = __builtin_amdgcn_mfma_f32_32x32x16_bf16(wh, xl0, accB0, 0, 0, 0);
      accB1 = __builtin_amdgcn_mfma_f32_32x32x16_bf16(wh, xl1, accB1, 0, 0, 0);
    }
  }

  int pxg = bx + (lane & 31);
  if (pxg < W_) {
    long base0 = (long)z * 64 * HW_ + (long)(by4 + 2 * rp) * W_ + pxg;
    long base1 = base0 + W_;
#pragma unroll
    for (int r = 0; r < 16; ++r) {
      int oc = mt * 32 + (r & 3) + 8 * (r >> 2) + 4 * g;
      part[base0 + (long)oc * HW_] = accA0[r] + accB0[r];
      part[base1 + (long)oc * HW_] = accA1[r] + accB1[r];
    }
  }
}

// ---------------------------------------------------------------------------
// conv_body (conv2): unchanged r16 structure, packed-bf16 h1 input.
// ---------------------------------------------------------------------------
template <int ICBT, int KG>
__device__ __forceinline__ void conv_body(
    const short* __restrict__ xhi, const short* __restrict__ xlo,
    const short* __restrict__ whi, const short* __restrict__ wlo,
    float* __restrict__ part, short* __restrict__ sx) {
  constexpr int NICB  = ICBT / KG;
  constexpr int TOTCH = NICB * 864;
  const int tid  = threadIdx.x;
  const int lane = tid & 63;
  const int wid  = tid >> 6;
  const int mt   = wid & 1;
  const int rp   = wid >> 1;
  const int g    = (lane >> 5) & 1;
  const int bx   = blockIdx.x * 32;
  const int by4  = blockIdx.y * 4;
  const int z    = blockIdx.z;
  const int kg   = z % KG;
  const int n    = z / KG;
  const int icb0 = kg * NICB;

#pragma unroll
  for (int i = 0; i < (TOTCH + 255) / 256; ++i) {
    int c = i * 256 + wid * 64 + lane;
    if (c < TOTCH) {
      int ii   = c / 864;
      int rem  = c - ii * 864;
      int hl   = rem / 432;
      int rem2 = rem - hl * 432;
      int r = rem2 / 72, k = rem2 - r * 72;
      const short* src = (hl ? xlo : xhi)
          + ((long)(n * ICBT + icb0 + ii) * PPX_ + (long)(by4 + r) * PROW_ + bx) * 16 + k * 8;
      __builtin_amdgcn_global_load_lds(src, &sx[c * 8], 16, 0, 0);
    }
  }
  __syncthreads();

  f32x16 accA0, accB0, accA1, accB1;
#pragma unroll
  for (int i = 0; i < 16; ++i) { accA0[i] = 0.f; accB0[i] = 0.f; accA1[i] = 0.f; accB1[i] = 0.f; }

#pragma unroll
  for (int ii = 0; ii < NICB; ++ii) {
#pragma unroll
    for (int tap = 0; tap < 9; ++tap) {
      const int dy = tap / 3, dx = tap % 3;
      const int sbase = ii * 6912 + (2 * rp + dy) * 576 + ((lane & 31) + dx) * 16 + g * 8;
      bf16x8 xh0 = *(const bf16x8*)&sx[sbase];
      bf16x8 xl0 = *(const bf16x8*)&sx[sbase + 3456];
      bf16x8 xh1 = *(const bf16x8*)&sx[sbase + 576];
      bf16x8 xl1 = *(const bf16x8*)&sx[sbase + 3456 + 576];
      long wi = ((long)((mt * 9 + tap) * ICBT + icb0 + ii)) * 512 + lane * 8;
      bf16x8 wh = *(const bf16x8*)(whi + wi);
      bf16x8 wl = *(const bf16x8*)(wlo + wi);
      accA0 = __builtin_amdgcn_mfma_f32_32x32x16_bf16(wh, xh0, accA0, 0, 0, 0);
      accA1 = __builtin_amdgcn_mfma_f32_32x32x16_bf16(wh, xh1, accA1, 0, 0, 0);
      accB0 = __builtin_amdgcn_mfma_f32_32x32x16_bf16(wl, xh0, accB0, 0, 0, 0);
      accB1 = __builtin_amdgcn_mfma_f32_32x32x16_bf16(wl, xh1, accB1, 0, 0, 0);
      accB0 = __builtin_amdgcn_mfma_f32_32x32x16_bf16(wh, xl0, accB0, 0, 0, 0);
      accB1 = __builtin_amdgcn_mfma_f32_32x32x16_bf16(wh, xl1, accB1, 0, 0, 0);
    }
  }

  int pxg = bx + (lane & 31);
  if (pxg < W_) {
    long base0 = (long)z * 64 * HW_ + (long)(by4 + 2 * rp) * W_ + pxg;
    long base1 = base0 + W_;
#pragma unroll
    for (int r = 0; r < 16; ++r) {
      int oc = mt * 32 + (r & 3) + 8 * (r >> 2) + 4 * g;
      part[base0 + (long)oc * HW_] = accA0[r] + accB0[r];
      part[base1 + (long)oc * HW_] = accA1[r] + accB1[r];
    }
  }
}

__global__ __launch_bounds__(256) void conv2_mfma(
    const short* __restrict__ xhi, const short* __restrict__ xlo,
    const short* __restrict__ whi, const short* __restrict__ wlo,
    float* __restrict__ part) {
  __shared__ alignas(16) short sx[1 * 6912];
  conv_body<4, 4>(xhi, xlo, whi, wlo, part, sx);
}

// ---------------------------------------------------------------------------
// combine1: h1 = lrelu(sum_kg part + bias) -> packed padded hi/lo (conv2 in).
// ---------------------------------------------------------------------------
template <int KG>
__global__ __launch_bounds__(256) void combine1(
    const float* __restrict__ part, const float* __restrict__ bias,
    short* __restrict__ ohi, short* __restrict__ olo) {
  __shared__ float sm[16][113];
  int bid = blockIdx.x;
  int y   = bid % H_;
  int icb = (bid / H_) % 4;
  int n   = bid / (H_ * 4);
  int tid = threadIdx.x;
  for (int i = tid; i < 16 * 112; i += 256) {
    int c = i / 112, x = i - c * 112;
    int oc = icb * 16 + c;
    long hw = (long)y * W_ + x;
    float v = bias[oc];
#pragma unroll
    for (int k = 0; k < KG; ++k)
      v += part[((long)(n * KG + k) * 64 + oc) * HW_ + hw];
    v = v > 0.f ? v : v * SLOPE_;
    sm[c][x] = v;
  }
  __syncthreads();
  if (tid < 224) {
    int px = tid >> 1, gg = tid & 1;
    unsigned hh[8], ll[8];
#pragma unroll
    for (int j = 0; j < 8; ++j) {
      float v = sm[gg * 8 + j][px];
      hh[j] = f2bf(v);
      ll[j] = f2bf(v - bf2f((unsigned short)hh[j]));
    }
    long o = ((long)(n * 4 + icb) * PPX_ + (long)(y + 1) * PROW_ + (px + 1)) * 16 + gg * 8;
    uint4 uh, ul;
    uh.x = hh[0] | (hh[1] << 16); uh.y = hh[2] | (hh[3] << 16);
    uh.z = hh[4] | (hh[5] << 16); uh.w = hh[6] | (hh[7] << 16);
    ul.x = ll[0] | (ll[1] << 16); ul.y = ll[2] | (ll[3] << 16);
    ul.z = ll[4] | (ll[5] << 16); ul.w = ll[6] | (ll[7] << 16);
    *(uint4*)(ohi + o) = uh;
    *(uint4*)(olo + o) = ul;
  }
}

// ---------------------------------------------------------------------------
// combine2p: final = sum_kg part + bias + resid(packed); writes BOTH the
// packed working slice (for subsequent steps) and NCHW d_out (validated).
// Block = (n, cg, y); LDS transpose for coalescing on all sides.
// ---------------------------------------------------------------------------
template <int KG>
__global__ __launch_bounds__(256) void combine2p(
    const float* __restrict__ part, const float* __restrict__ bias,
    float* __restrict__ WfT,   // packed t-slice, n-stride NSTW_
    float* __restrict__ out) { // NCHW full tensor; t-slice offset pre-added
  __shared__ float sm[16][113];
  int bid = blockIdx.x;
  int y   = bid % H_;
  int cg  = (bid / H_) % 4;
  int n   = bid / (H_ * 4);
  int tid = threadIdx.x;
  for (int i = tid; i < 16 * 112; i += 256) {
    int c = i / 112, x = i - c * 112;
    int oc = cg * 16 + c;
    long hw = (long)y * W_ + x;
    float v = bias[oc];
#pragma unroll
    for (int k = 0; k < KG; ++k)
      v += part[((long)(n * KG + k) * 64 + oc) * HW_ + hw];
    sm[c][x] = v;
  }
  __syncthreads();
  if (tid < 224) {
    int px = tid >> 1, gg = tid & 1;
    float* q = WfT + (long)n * NSTW_ + (long)cg * PHW_ + ((long)y * W_ + px) * 16 + gg * 8;
    float4 ra = *(const float4*)q, rb = *(const float4*)(q + 4);
    float f0 = sm[gg * 8 + 0][px] + ra.x;
    float f1v = sm[gg * 8 + 1][px] + ra.y;
    float f2v = sm[gg * 8 + 2][px] + ra.z;
    float f3 = sm[gg * 8 + 3][px] + ra.w;
    float f4 = sm[gg * 8 + 4][px] + rb.x;
    float f5 = sm[gg * 8 + 5][px] + rb.y;
    float f6 = sm[gg * 8 + 6][px] + rb.z;
    float f7 = sm[gg * 8 + 7][px] + rb.w;
    sm[gg * 8 + 0][px] = f0; sm[gg * 8 + 1][px] = f1v;
    sm[gg * 8 + 2][px] = f2v; sm[gg * 8 + 3][px] = f3;
    sm[gg * 8 + 4][px] = f4; sm[gg * 8 + 5][px] = f5;
    sm[gg * 8 + 6][px] = f6; sm[gg * 8 + 7][px] = f7;
    *(float4*)q = float4{f0, f1v, f2v, f3};
    *(float4*)(q + 4) = float4{f4, f5, f6, f7};
  }
  __syncthreads();
  for (int i = tid; i < 16 * 112; i += 256) {
    int c = i / 112, x = i - c * 112;
    out[(long)n * T_ * C_ * HW_ + (long)(cg * 16 + c) * HW_ + (long)y * W_ + x] = sm[c][x];
  }
}

// ---------------------------------------------------------------------------
// Host-side orchestration
// ---------------------------------------------------------------------------
constexpr int KG1 = 6;
constexpr int KG2 = 4;

struct Bufs {
  float* part; float* Wf;
  short *h1hi, *h1lo, *w1hi, *w1lo, *w2hi, *w2lo;
};

static void run_step(float* out, const float* flows, int t, bool fwd, int i,
                     const float* b1, const float* b2, const Bufs& B,
                     hipStream_t stream) {
  const float* currP = B.Wf + (long)t * 4 * PHW_;
  const float* p1P = nullptr;
  const float* p2P = nullptr;
  const float* f1 = nullptr;
  const float* f2 = nullptr;
  if (fwd) {
    if (t >= 1) { p1P = B.Wf + (long)(t - 1) * 4 * PHW_; f1 = flows + (long)(t - 1) * 2 * HW_; }
    if (t >= 2) { p2P = B.Wf + (long)(t - 2) * 4 * PHW_; f2 = flows + (long)(t - 2) * 2 * HW_; }
  } else {
    if (i >= 1) { p1P = B.Wf + (long)(t + 1) * 4 * PHW_; f1 = flows + (long)(t + 1) * 2 * HW_; }
    if (i >= 2) { p2P = B.Wf + (long)(t + 2) * 4 * PHW_; f2 = flows + (long)(t + 2) * 2 * HW_; }
  }

  warp_conv1<<<dim3(4, 28, N_ * KG1), 256, 0, stream>>>(
      currP, p1P, p2P, f1, f2, B.w1hi, B.w1lo, B.part);
  combine1<KG1><<<N_ * 4 * H_, 256, 0, stream>>>(B.part, b1, B.h1hi, B.h1lo);
  conv2_mfma<<<dim3(4, 28, N_ * KG2), 256, 0, stream>>>(
      B.h1hi, B.h1lo, B.w2hi, B.w2lo, B.part);
  combine2p<KG2><<<N_ * 4 * H_, 256, 0, stream>>>(
      B.part, b2, B.Wf + (long)t * 4 * PHW_, out + (long)t * C_ * HW_);
}

extern "C" void kernel_launch(void* const* d_in, const int* in_sizes, int n_in,
                              void* d_out, int out_size, void* d_ws, size_t ws_size,
                              hipStream_t stream) {
  const float* feats = (const float*)d_in[0];
  const float* fflow = (const float*)d_in[1];
  const float* bflow = (const float*)d_in[2];
  const float* W1 = (const float*)d_in[3];
  const float* b1 = (const float*)d_in[4];
  const float* W2 = (const float*)d_in[5];
  const float* b2 = (const float*)d_in[6];
  float* out = (float*)d_out;

  char* p = (char*)d_ws;
  auto carve = [&](size_t bytes) {
    void* r = (void*)p;
    p += (bytes + 255) & ~(size_t)255;
    return r;
  };
  Bufs B;
  size_t h1pack_sh = (size_t)N_ * 4 * PPX_ * 16;
  B.part = (float*)carve(sizeof(float) * (size_t)KG1 * N_ * 64 * HW_);
  B.Wf   = (float*)carve(sizeof(float) * (size_t)N_ * T_ * 4 * PHW_);
  B.h1hi = (short*)carve(2 * h1pack_sh);
  B.h1lo = (short*)carve(2 * h1pack_sh);
  B.w1hi = (short*)carve(2 * (size_t)(2 * 9 * 12 * 64 * 8));
  B.w1lo = (short*)carve(2 * (size_t)(2 * 9 * 12 * 64 * 8));
  B.w2hi = (short*)carve(2 * (size_t)(2 * 9 * 4 * 64 * 8));
  B.w2lo = (short*)carve(2 * (size_t)(2 * 9 * 4 * 64 * 8));

  // Prologue: pack feats into the working layout; zero h1 pad rings; weights.
  pack_feats<<<N_ * T_ * 4 * H_, 256, 0, stream>>>(feats, B.Wf);
  {
    constexpr int PXH = 2 * PROW_ + 112 * 19;
    int total = 8 * 2 * PXH;
    halo_zero<<<(total + 255) / 256, 256, 0, stream>>>(B.h1hi, B.h1lo);
  }
  pack_w<<<(2 * 9 * 12 * 64 * 8 + 255) / 256, 256, 0, stream>>>(W1, B.w1hi, B.w1lo, 12);
  pack_w<<<(2 * 9 * 4 * 64 * 8 + 255) / 256, 256, 0, stream>>>(W2, B.w2hi, B.w2lo, 4);

  for (int t = 0; t < T_; ++t)
    run_step(out, fflow, t, true, t, b1, b2, B, stream);
  for (int i = 0; i < T_; ++i) {
    int t = T_ - 1 - i;
    run_step(out, bflow, t, false, i, b1, b2, B, stream);
  }
}